// Round 3
// baseline (503.571 us; speedup 1.0000x reference)
//
#include <hip/hip_runtime.h>
#include <hip/hip_bf16.h>
#include <stdint.h>

#define NN 4096
#define KNN 20
#define LRK 40
#define EPN 60
#define NE (NN*EPN)
#define SPHC 35
#define BBCC 32
#define NHEAD 8
#define HVD 64
#define HCD 32
#define AINC 102
#define LT 9

#define EXCL_POOL 0xFFFFFFFEu
#define EXCL_DONE 0xFFFFFFFFu

// ---- bit-exact replica of jax.random.gumbel(key(1), (4096,4096))[i,j] (up to logf rounding) ----
__device__ __forceinline__ float gumbel_f(int i, int j) {
  // flat index f = i*4096+j; halves pairing: (c, c+2^23), word = (i>=2048)
  uint32_t c = ((uint32_t)(i & 2047) << 12) | (uint32_t)j;
  const uint32_t ks0 = 0u, ks1 = 1u, ks2 = 0x1BD11BDBu; // 0^1^0x1BD11BDA
  uint32_t x0 = c + ks0;
  uint32_t x1 = (c + 0x800000u) + ks1;
#define TF_R(r) { x0 += x1; x1 = (x1 << (r)) | (x1 >> (32 - (r))); x1 ^= x0; }
  TF_R(13) TF_R(15) TF_R(26) TF_R(6)   x0 += ks1; x1 += ks2 + 1u;
  TF_R(17) TF_R(29) TF_R(16) TF_R(24)  x0 += ks2; x1 += ks0 + 2u;
  TF_R(13) TF_R(15) TF_R(26) TF_R(6)   x0 += ks0; x1 += ks1 + 3u;
  TF_R(17) TF_R(29) TF_R(16) TF_R(24)  x0 += ks1; x1 += ks2 + 4u;
  TF_R(13) TF_R(15) TF_R(26) TF_R(6)   x0 += ks2; x1 += ks0 + 5u;
#undef TF_R
  uint32_t b = (i >= 2048) ? x1 : x0;
  float u = __uint_as_float((b >> 9) | 0x3F800000u) - 1.0f; // [0,1)
  u = u + 1.17549435e-38f;  // JAX: u*(1-tiny)+tiny with (1-tiny)==1 in f32
  return -logf(-logf(u));
}

// ---- P0: precompute Xw=(x,y,z,|x|^2) f32, batch/mask word, inv[n][35] ----
__global__ void prep_kernel(const float* __restrict__ X,
                            const int* __restrict__ batch,
                            const int* __restrict__ xmask,
                            const int* __restrict__ nmask,
                            const float* __restrict__ bbf,
                            float4* __restrict__ Xw, uint32_t* __restrict__ bm,
                            float* __restrict__ inv) {
#pragma clang fp contract(off)
  int n = blockIdx.x * blockDim.x + threadIdx.x;
  if (n >= NN) return;
  float x = X[n*3+0], y = X[n*3+1], z = X[n*3+2];
  float x2 = (x*x + y*y) + z*z;   // match np sum order, no fma
  Xw[n] = make_float4(x, y, z, x2);
  bm[n] = ((uint32_t)batch[n] << 1) | (xmask[n] ? 1u : 0u);
  float* ip = inv + (size_t)n * SPHC;
  for (int c = 0; c < BBCC; c++) ip[c] = bbf[(size_t)(n*LT + 0)*BBCC + c];
  ip[32] = 0.f; ip[33] = 0.f; ip[34] = nmask[n] ? 1.0f : 0.0f;
}

// ---- K1: per-row knn20 + gumbel-lr40 selection ----
__global__ __launch_bounds__(256) void select_kernel(const float4* __restrict__ Xw,
                                                     const uint32_t* __restrict__ bm,
                                                     int* __restrict__ srcO) {
#pragma clang fp contract(off)
  __shared__ uint32_t val[NN];               // 16KB: d2 bits / score keys
  __shared__ unsigned long long tree[256];
  __shared__ unsigned long long wred[4];
  __shared__ int sel[EPN];
  const int i = blockIdx.x, tid = threadIdx.x;
  const float4 xi = Xw[i];
  const uint32_t bmi = bm[i];

  for (int j = tid; j < NN; j += 256) {
    float4 xj = Xw[j];
    uint32_t bmj = bm[j];
    bool inval = (((bmj ^ bmi) >> 1) != 0u) || (((bmj | bmi) & 1u) != 0u) || (j == i);
    float dot = xi.x*xj.x + xi.y*xj.y + xi.z*xj.z;
    float d2r = (xi.w + xj.w) - 2.0f*dot;
    float d2 = d2r > 0.0f ? d2r : 0.0f;      // force +0, never -0
    val[j] = inval ? EXCL_POOL : __float_as_uint(d2);
  }
  // build tournament tree: per-thread min over its stripe (j == tid mod 256)
  {
    unsigned long long best = ~0ull;
    for (int q = 0; q < 16; q++) {
      int j = tid + (q << 8);
      unsigned long long k = ((unsigned long long)val[j] << 32) | (unsigned)j;
      best = k < best ? k : best;
    }
    tree[tid] = best;
  }
  __syncthreads();

  for (int ph = 0; ph < 2; ph++) {
    const int base = ph ? KNN : 0;
    const int cnt  = ph ? LRK : KNN;
    for (int s = 0; s < cnt; s++) {
      unsigned long long m = tree[tid];
      #pragma unroll
      for (int off = 32; off > 0; off >>= 1) {
        unsigned long long o = __shfl_xor(m, off, 64);
        m = o < m ? o : m;
      }
      if ((tid & 63) == 0) wred[tid >> 6] = m;
      __syncthreads();
      unsigned long long g = wred[0];
      g = wred[1] < g ? wred[1] : g;
      g = wred[2] < g ? wred[2] : g;
      g = wred[3] < g ? wred[3] : g;
      int j = (int)(uint32_t)(g & 0xFFFFFFFFull);
      if (tid == 0) sel[base + s] = j;
      if (tid == (j & 255)) {                 // owner: consume + rebuild stripe
        val[j] = EXCL_DONE;
        unsigned long long best = ~0ull;
        for (int q = 0; q < 16; q++) {
          int jj = tid + (q << 8);
          unsigned long long k = ((unsigned long long)val[jj] << 32) | (unsigned)jj;
          best = k < best ? k : best;
        }
        tree[tid] = best;
      }
      __syncthreads();
    }
    if (ph == 0) {
      // transform d2 -> descending score key: score = -1.5*log(d2+1e-6) + gumbel
      for (int j = tid; j < NN; j += 256) {
        uint32_t v = val[j];
        uint32_t skey;
        if (v >= EXCL_POOL) skey = EXCL_POOL;  // invalid OR knn-consumed -> -BIG tie pool
        else {
          float d2 = __uint_as_float(v);
          float sc = -1.5f * logf(d2 + 1e-6f) + gumbel_f(i, j);
          uint32_t u = __float_as_uint(sc);
          uint32_t fl = (u & 0x80000000u) ? ~u : (u | 0x80000000u); // ascending order key
          skey = ~fl;                                               // descending (min = max score)
        }
        val[j] = skey;
      }
      unsigned long long best = ~0ull;
      for (int q = 0; q < 16; q++) {
        int jj = tid + (q << 8);
        unsigned long long k = ((unsigned long long)val[jj] << 32) | (unsigned)jj;
        best = k < best ? k : best;
      }
      tree[tid] = best;
      __syncthreads();
    }
  }
  if (tid < EPN) srcO[(size_t)i * EPN + tid] = sel[tid];
}

// ---- K2: V[n,l,:] = so3_linear(node, wv, bv) ----
__global__ __launch_bounds__(256) void vmat_kernel(const float* __restrict__ bbf,
                                                   const float* __restrict__ bbrel,
                                                   const int* __restrict__ nmask,
                                                   const float* __restrict__ wv,
                                                   const float* __restrict__ bv,
                                                   float* __restrict__ V) {
  int row = blockIdx.x * 4 + (threadIdx.x >> 6);
  int d = threadIdx.x & 63;
  if (row >= NN * LT) return;
  int n = row / LT, l = row % LT;
  int li = (l == 0) ? 0 : (l < 4 ? 1 : 2);
  const float* w = wv + (size_t)li * SPHC * HVD;
  float acc = (l == 0) ? bv[d] : 0.f;
  const float* nb = bbf + (size_t)(n*LT + l) * BBCC;
  for (int c = 0; c < BBCC; c++) acc = fmaf(nb[c], w[c*HVD + d], acc);
  if (l >= 1 && l < 4) {
    for (int b = 0; b < 3; b++)
      acc = fmaf(bbrel[(size_t)(n*3 + b)*3 + (l-1)], w[(32+b)*HVD + d], acc);
  }
  if (l == 0) acc = fmaf(nmask[n] ? 1.f : 0.f, w[34*HVD + d], acc);
  V[(size_t)row * HVD + d] = acc;
}

// ---- K3: edge MLP -> logits (8 per edge) ----
__global__ __launch_bounds__(256) void edge_kernel(const int* __restrict__ src,
                                                   const float4* __restrict__ Xw,
                                                   const float* __restrict__ inv,
                                                   const float* __restrict__ w1,
                                                   const float* __restrict__ b1,
                                                   const float* __restrict__ w2,
                                                   const float* __restrict__ b2,
                                                   float* __restrict__ logitO) {
  __shared__ float w1f[AINC][HCD];
  __shared__ float w2f[HCD][NHEAD];
  __shared__ float b1f[HCD];
  __shared__ float b2f[NHEAD];
  __shared__ float ain[8][AINC];
  __shared__ float hbuf[8][HCD];
  int tid = threadIdx.x;
  for (int q = tid; q < AINC*HCD; q += 256) w1f[q / HCD][q % HCD] = w1[q];
  for (int q = tid; q < HCD*NHEAD; q += 256) w2f[q / NHEAD][q % NHEAD] = w2[q];
  if (tid < HCD) b1f[tid] = b1[tid];
  if (tid < NHEAD) b2f[tid] = b2[tid];
  int sub = tid >> 5, t = tid & 31;
  int e = blockIdx.x * 8 + sub;
  int d = e / EPN;
  int s = src[e];
  for (int k = t; k < SPHC; k += 32) {
    ain[sub][k]        = inv[(size_t)s * SPHC + k];
    ain[sub][SPHC + k] = inv[(size_t)d * SPHC + k];
  }
  float4 xs = Xw[s], xd = Xw[d];
  float dx = xs.x - xd.x, dy = xs.y - xd.y, dz = xs.z - xd.z;
  float dist = sqrtf(dx*dx + dy*dy + dz*dz);
  if (t < 16) {
    float mu = (20.0f / 15.0f) * (float)t;
    float zz = (dist - mu) / 1.25f;
    ain[sub][70 + t] = expf(-zz * zz);
  } else {
    int k = t - 16;
    float del = (float)(s - d);
    float fr = expf((float)(2 * (k & 7)) * -0.5756462732485115f);
    float a = del * fr;
    ain[sub][86 + k] = (k < 8) ? cosf(a) : sinf(a);
  }
  __syncthreads();
  float a = b1f[t];
  for (int k = 0; k < AINC; k++) a = fmaf(ain[sub][k], w1f[k][t], a);
  hbuf[sub][t] = a / (1.f + expf(-a));  // silu
  __syncthreads();
  if (tid < 64) {
    int e2 = tid >> 3, hh = tid & 7;
    float lg = b2f[hh];
    for (int c = 0; c < HCD; c++) lg = fmaf(hbuf[e2][c], w2f[c][hh], lg);
    logitO[(size_t)(blockIdx.x * 8 + e2) * NHEAD + hh] = lg;
  }
}

// ---- K4: per-node softmax, aggregate, SO3 output chain ----
__global__ __launch_bounds__(64) void node_kernel(const int* __restrict__ src,
                                                  const float* __restrict__ logit,
                                                  const float* __restrict__ V,
                                                  const float* __restrict__ wo,
                                                  const float* __restrict__ bo,
                                                  const float* __restrict__ wg,
                                                  const float* __restrict__ bg,
                                                  const float* __restrict__ wf,
                                                  const float* __restrict__ bfb,
                                                  const float* __restrict__ w_xca,
                                                  const float* __restrict__ w_gate,
                                                  const float* __restrict__ b_gate,
                                                  const float* __restrict__ w_bb,
                                                  const float* __restrict__ X,
                                                  const float* __restrict__ bbrel,
                                                  const int* __restrict__ nmask,
                                                  float* __restrict__ out) {
  const int n = blockIdx.x, t = threadIdx.x;
  __shared__ float alpha[EPN][NHEAD];
  __shared__ int slist[EPN];
  __shared__ float agg[LT][HVD];
  __shared__ float o0[LT][BBCC];
  __shared__ float ofin[LT][BBCC];
  __shared__ float gate[BBCC];
  if (t < EPN) slist[t] = src[(size_t)n * EPN + t];
  for (int q = t; q < EPN * NHEAD; q += 64) alpha[q / NHEAD][q % NHEAD] = logit[(size_t)n * 480 + q];
  __syncthreads();
  if (t < NHEAD) {
    float m = -1e30f;
    for (int e = 0; e < EPN; e++) m = fmaxf(m, alpha[e][t]);
    float Z = 0.f;
    for (int e = 0; e < EPN; e++) { float p = expf(alpha[e][t] - m); alpha[e][t] = p; Z += p; }
    float iz = 1.f / (Z + 1e-9f);
    for (int e = 0; e < EPN; e++) alpha[e][t] *= iz;
  }
  __syncthreads();
  {
    const int h = t >> 3;
    float acc[LT];
    #pragma unroll
    for (int l = 0; l < LT; l++) acc[l] = 0.f;
    for (int e = 0; e < EPN; e++) {
      const float* Vp = V + (size_t)slist[e] * (LT * HVD) + t;
      float a = alpha[e][h];
      #pragma unroll
      for (int l = 0; l < LT; l++) acc[l] = fmaf(a, Vp[l * HVD], acc[l]);
    }
    #pragma unroll
    for (int l = 0; l < LT; l++) agg[l][t] = acc[l];
  }
  __syncthreads();
  for (int idx = t; idx < LT * BBCC; idx += 64) {
    int l = idx >> 5, d = idx & 31;
    int li = (l == 0) ? 0 : (l < 4 ? 1 : 2);
    float a = (l == 0) ? bo[d] : 0.f;
    const float* w = wo + (size_t)li * HVD * BBCC;
    for (int c = 0; c < HVD; c++) a = fmaf(agg[l][c], w[c * BBCC + d], a);
    o0[l][d] = a;
  }
  __syncthreads();
  if (t < BBCC) {
    float a = bg[t];
    for (int c = 0; c < BBCC; c++) a = fmaf(o0[0][c], wg[c * BBCC + t], a);
    gate[t] = a / (1.f + expf(-a));
  }
  __syncthreads();
  for (int idx = t; idx < LT * BBCC; idx += 64) {
    int l = idx >> 5, d = idx & 31;
    int li = (l == 0) ? 0 : (l < 4 ? 1 : 2);
    float a = (l == 0) ? bfb[d] : 0.f;
    const float* w = wf + (size_t)li * BBCC * BBCC;
    for (int c = 0; c < BBCC; c++) a = fmaf(o0[l][c], w[c * BBCC + d], a);
    float r = o0[l][d] + a * gate[d];
    ofin[l][d] = r;
    out[49152 + (size_t)n * 288 + idx] = r;
  }
  __syncthreads();
  // g2 = softplus(ofin[0] @ w_gate + b_gate) (computed redundantly by all lanes)
  float a2 = b_gate[0];
  for (int c = 0; c < BBCC; c++) a2 = fmaf(ofin[0][c], w_gate[c], a2);
  float g2 = fmaxf(a2, 0.f) + log1pf(expf(-fabsf(a2)));
  bool noise = nmask[n] != 0;
  if (t < 3) {
    float a = 0.f;
    for (int d2 = 0; d2 < BBCC; d2++) a = fmaf(ofin[1 + t][d2], w_xca[32 + d2], a);
    float nx = X[n * 3 + t] + (noise ? a * g2 : 0.f);
    out[(size_t)n * 3 + t] = nx;
  }
  if (t < 9) {
    int b = t / 3, c = t % 3;
    float a = 0.f;
    for (int d2 = 0; d2 < BBCC; d2++) a = fmaf(ofin[1 + c][d2], w_bb[(32 + d2) * 3 + b], a);
    float nb = bbrel[(size_t)(n * 3 + b) * 3 + c] + (noise ? a : 0.f);
    out[12288 + (size_t)n * 9 + b * 3 + c] = nb;
  }
}

extern "C" void kernel_launch(void* const* d_in, const int* in_sizes, int n_in,
                              void* d_out, int out_size, void* d_ws, size_t ws_size,
                              hipStream_t stream) {
  (void)in_sizes; (void)n_in; (void)out_size;
  const float* X      = (const float*)d_in[0];
  const float* bbrel  = (const float*)d_in[1];
  const float* bbf    = (const float*)d_in[2];
  const int* batch    = (const int*)d_in[3];
  const int* xmask    = (const int*)d_in[4];
  const int* nmask    = (const int*)d_in[5];
  const float* w1     = (const float*)d_in[6];
  const float* b1     = (const float*)d_in[7];
  const float* w2     = (const float*)d_in[8];
  const float* b2     = (const float*)d_in[9];
  const float* wv     = (const float*)d_in[10];
  const float* bv     = (const float*)d_in[11];
  const float* wo     = (const float*)d_in[12];
  const float* bo     = (const float*)d_in[13];
  const float* wg     = (const float*)d_in[14];
  const float* bg     = (const float*)d_in[15];
  const float* wf     = (const float*)d_in[16];
  const float* bfb    = (const float*)d_in[17];
  const float* w_xca  = (const float*)d_in[18];
  // d_in[19] = b_xca: only affects l=0 row of upd_x, which is sliced away (rows 1:4 used)
  const float* w_gate = (const float*)d_in[20];
  const float* b_gate = (const float*)d_in[21];
  const float* w_bb   = (const float*)d_in[22];
  // d_in[23] = b_bb: same (l=0 only), unused

  if (ws_size < 18939904) return;
  char* ws = (char*)d_ws;
  float4*   Xw    = (float4*)(ws + 0);          //  64KB
  uint32_t* bmp   = (uint32_t*)(ws + 65536);    //  16KB
  float*    inv   = (float*)(ws + 81920);       // 560KB
  int*      srcl  = (int*)(ws + 655360);        // 960KB
  float*    logit = (float*)(ws + 1638400);     // 7.5MB
  float*    V     = (float*)(ws + 9502720);     // 9.0MB
  float*    out   = (float*)d_out;

  prep_kernel<<<NN / 256, 256, 0, stream>>>(X, batch, xmask, nmask, bbf, Xw, bmp, inv);
  select_kernel<<<NN, 256, 0, stream>>>(Xw, bmp, srcl);
  vmat_kernel<<<(NN * LT) / 4, 256, 0, stream>>>(bbf, bbrel, nmask, wv, bv, V);
  edge_kernel<<<NE / 8, 256, 0, stream>>>(srcl, Xw, inv, w1, b1, w2, b2, logit);
  node_kernel<<<NN, 64, 0, stream>>>(srcl, logit, V, wo, bo, wg, bg, wf, bfb,
                                     w_xca, w_gate, b_gate, w_bb, X, bbrel, nmask, out);
}

// Round 4
// 370.693 us; speedup vs baseline: 1.3585x; 1.3585x over previous
//
#include <hip/hip_runtime.h>
#include <hip/hip_bf16.h>
#include <stdint.h>

#define NN 4096
#define CS 2048           // chain size (NN / CHAINS)
#define KNN 20
#define LRK 40
#define EPN 60
#define NE (NN*EPN)
#define SPHC 35
#define BBCC 32
#define NHEAD 8
#define HVD 64
#define HCD 32
#define AINC 102
#define LT 9

#define INVAL_D2 0xFFFFFFFEu   // invalid pair (mask/eye): +BIG in reference
#define CONSUMED 0xFFFFFFFFu   // knn-consumed (or invalid) for LR phase

// ---- bit-exact replica of jax.random.gumbel(key(1), (4096,4096))[i,j] (up to logf rounding) ----
__device__ __forceinline__ float gumbel_f(int i, int j) {
  uint32_t c = ((uint32_t)(i & 2047) << 12) | (uint32_t)j;
  const uint32_t ks0 = 0u, ks1 = 1u, ks2 = 0x1BD11BDBu; // 0^1^0x1BD11BDA
  uint32_t x0 = c + ks0;
  uint32_t x1 = (c + 0x800000u) + ks1;
#define TF_R(r) { x0 += x1; x1 = (x1 << (r)) | (x1 >> (32 - (r))); x1 ^= x0; }
  TF_R(13) TF_R(15) TF_R(26) TF_R(6)   x0 += ks1; x1 += ks2 + 1u;
  TF_R(17) TF_R(29) TF_R(16) TF_R(24)  x0 += ks2; x1 += ks0 + 2u;
  TF_R(13) TF_R(15) TF_R(26) TF_R(6)   x0 += ks0; x1 += ks1 + 3u;
  TF_R(17) TF_R(29) TF_R(16) TF_R(24)  x0 += ks1; x1 += ks2 + 4u;
  TF_R(13) TF_R(15) TF_R(26) TF_R(6)   x0 += ks2; x1 += ks0 + 5u;
#undef TF_R
  uint32_t b = (i >= 2048) ? x1 : x0;
  float u = __uint_as_float((b >> 9) | 0x3F800000u) - 1.0f; // [0,1)
  u = u + 1.17549435e-38f;
  return -logf(-logf(u));
}

// ---- P0: precompute Xw=(x,y,z,|x|^2) f32, batch/mask word, inv[n][35] ----
__global__ void prep_kernel(const float* __restrict__ X,
                            const int* __restrict__ batch,
                            const int* __restrict__ xmask,
                            const int* __restrict__ nmask,
                            const float* __restrict__ bbf,
                            float4* __restrict__ Xw, uint32_t* __restrict__ bm,
                            float* __restrict__ inv) {
#pragma clang fp contract(off)
  int n = blockIdx.x * blockDim.x + threadIdx.x;
  if (n >= NN) return;
  float x = X[n*3+0], y = X[n*3+1], z = X[n*3+2];
  float x2 = (x*x + y*y) + z*z;
  Xw[n] = make_float4(x, y, z, x2);
  bm[n] = ((uint32_t)batch[n] << 1) | (xmask[n] ? 1u : 0u);
  float* ip = inv + (size_t)n * SPHC;
  for (int c = 0; c < BBCC; c++) ip[c] = bbf[(size_t)(n*LT + 0)*BBCC + c];
  ip[32] = 0.f; ip[33] = 0.f; ip[34] = nmask[n] ? 1.0f : 0.0f;
}

// ---- exact k-th-smallest radix select over val[0..CS) + compaction into sel[base..base+k) ----
__device__ __forceinline__ void radix_select(uint32_t* val, uint32_t* hist,
                                             uint32_t* sh, uint32_t* eqpos,
                                             int* sel, int k, int base, int cb, int tid) {
  uint32_t vpart = 0, rk = (uint32_t)k;
  for (int shift = 24; shift >= 0; shift -= 8) {
    hist[tid] = 0;
    __syncthreads();
    #pragma unroll
    for (int q = 0; q < 8; q++) {
      uint32_t key = val[tid + (q << 8)];
      if ((((uint64_t)(key ^ vpart)) >> (shift + 8)) == 0)
        atomicAdd(&hist[(key >> shift) & 255u], 1u);
    }
    __syncthreads();
    if (tid < 64) {
      uint32_t c0 = hist[tid*4+0], c1 = hist[tid*4+1], c2 = hist[tid*4+2], c3 = hist[tid*4+3];
      uint32_t s = c0 + c1 + c2 + c3;
      uint32_t cum = s;
      #pragma unroll
      for (int off = 1; off < 64; off <<= 1) {
        uint32_t o = __shfl_up(cum, off, 64);
        if (tid >= off) cum += o;
      }
      uint32_t cumprev = cum - s;
      if (rk > cumprev && rk <= cum) {       // exactly one lane
        uint32_t r = rk - cumprev, dsel, sub;
        if (r <= c0)            { dsel = 0; sub = 0; }
        else if (r <= c0+c1)    { dsel = 1; sub = c0; }
        else if (r <= c0+c1+c2) { dsel = 2; sub = c0 + c1; }
        else                    { dsel = 3; sub = c0 + c1 + c2; }
        sh[0] = tid*4u + dsel;
        sh[1] = r - sub;
      }
    }
    __syncthreads();
    vpart |= (sh[0] << shift);
    rk = sh[1];
  }
  const uint32_t vstar = vpart;              // exact k-th smallest; rk = #eq-valued to take
  if (tid == 0) { sh[2] = 0; sh[3] = 0; }
  __syncthreads();
  #pragma unroll
  for (int q = 0; q < 8; q++) {
    int pos = tid + (q << 8);
    uint32_t key = val[pos];
    if (key < vstar) {
      uint32_t slot = atomicAdd(&sh[2], 1u);
      sel[base + slot] = cb + pos;
    } else if (key == vstar) {
      uint32_t t2 = atomicAdd(&sh[3], 1u);
      if (t2 < 64) eqpos[t2] = (uint32_t)pos;
    }
  }
  __syncthreads();
  if (tid == 0) {                            // ties at v*: take in ascending index order
    int have = (int)sh[2];
    int m = (int)sh[3]; if (m > 64) m = 64;
    for (int a = 1; a < m; a++) {
      uint32_t p = eqpos[a]; int b = a - 1;
      while (b >= 0 && eqpos[b] > p) { eqpos[b+1] = eqpos[b]; b--; }
      eqpos[b+1] = p;
    }
    for (int a = 0; a < m && have < k; a++) sel[base + have++] = cb + (int)eqpos[a];
  }
  __syncthreads();
}

// ---- K1: per-row knn20 + gumbel-lr40 via chain-restricted radix select ----
__global__ __launch_bounds__(256) void select_kernel(const float4* __restrict__ Xw,
                                                     const uint32_t* __restrict__ bm,
                                                     int* __restrict__ srcO) {
#pragma clang fp contract(off)
  __shared__ uint32_t val[CS];     // 8KB
  __shared__ uint32_t hist[256];   // 1KB
  __shared__ uint32_t sh[4];
  __shared__ uint32_t eqpos[64];
  __shared__ int sel[EPN];
  const int i = blockIdx.x, tid = threadIdx.x;
  const uint32_t bmi = bm[i];

  if (bmi & 1u) {                  // x_masked row: all candidates tie -> global indices 0..k-1
    if (tid < KNN) srcO[(size_t)i * EPN + tid] = tid;
    else if (tid < EPN) srcO[(size_t)i * EPN + tid] = tid - KNN;
    return;
  }
  const int cb = (int)(bmi >> 1) * CS;
  const float4 xi = Xw[i];

  #pragma unroll
  for (int q = 0; q < 8; q++) {
    int pos = tid + (q << 8);
    int j = cb + pos;
    float4 xj = Xw[j];
    uint32_t bmj = bm[j];
    bool inval = ((bmj & 1u) != 0u) || (j == i);
    float dot = xi.x*xj.x + xi.y*xj.y + xi.z*xj.z;
    float d2r = (xi.w + xj.w) - 2.0f*dot;
    float d2 = d2r > 0.0f ? d2r : 0.0f;
    val[pos] = inval ? INVAL_D2 : __float_as_uint(d2);
  }
  __syncthreads();

  radix_select(val, hist, sh, eqpos, sel, KNN, 0, cb, tid);

  // mark knn-consumed before score transform
  if (tid < KNN) val[sel[tid] - cb] = CONSUMED;
  __syncthreads();

  // transform d2 -> descending-score order key
  #pragma unroll
  for (int q = 0; q < 8; q++) {
    int pos = tid + (q << 8);
    uint32_t v = val[pos];
    uint32_t skey;
    if (v >= INVAL_D2) skey = CONSUMED;
    else {
      float d2 = __uint_as_float(v);
      float sc = -1.5f * logf(d2 + 1e-6f) + gumbel_f(i, cb + pos);
      uint32_t u = __float_as_uint(sc);
      uint32_t fl = (u & 0x80000000u) ? ~u : (u | 0x80000000u);
      skey = ~fl;                   // min key == max score
    }
    val[pos] = skey;
  }
  __syncthreads();

  radix_select(val, hist, sh, eqpos, sel, LRK, KNN, cb, tid);

  if (tid < EPN) srcO[(size_t)i * EPN + tid] = sel[tid];
}

// ---- K2: V[n,l,:] = so3_linear(node, wv, bv) ----
__global__ __launch_bounds__(256) void vmat_kernel(const float* __restrict__ bbf,
                                                   const float* __restrict__ bbrel,
                                                   const int* __restrict__ nmask,
                                                   const float* __restrict__ wv,
                                                   const float* __restrict__ bv,
                                                   float* __restrict__ V) {
  int row = blockIdx.x * 4 + (threadIdx.x >> 6);
  int d = threadIdx.x & 63;
  if (row >= NN * LT) return;
  int n = row / LT, l = row % LT;
  int li = (l == 0) ? 0 : (l < 4 ? 1 : 2);
  const float* w = wv + (size_t)li * SPHC * HVD;
  float acc = (l == 0) ? bv[d] : 0.f;
  const float* nb = bbf + (size_t)(n*LT + l) * BBCC;
  for (int c = 0; c < BBCC; c++) acc = fmaf(nb[c], w[c*HVD + d], acc);
  if (l >= 1 && l < 4) {
    for (int b = 0; b < 3; b++)
      acc = fmaf(bbrel[(size_t)(n*3 + b)*3 + (l-1)], w[(32+b)*HVD + d], acc);
  }
  if (l == 0) acc = fmaf(nmask[n] ? 1.f : 0.f, w[34*HVD + d], acc);
  V[(size_t)row * HVD + d] = acc;
}

// ---- K3: edge MLP -> logits (8 per edge) ----
__global__ __launch_bounds__(256) void edge_kernel(const int* __restrict__ src,
                                                   const float4* __restrict__ Xw,
                                                   const float* __restrict__ inv,
                                                   const float* __restrict__ w1,
                                                   const float* __restrict__ b1,
                                                   const float* __restrict__ w2,
                                                   const float* __restrict__ b2,
                                                   float* __restrict__ logitO) {
  __shared__ float w1f[AINC][HCD];
  __shared__ float w2f[HCD][NHEAD];
  __shared__ float b1f[HCD];
  __shared__ float b2f[NHEAD];
  __shared__ float ain[8][AINC];
  __shared__ float hbuf[8][HCD];
  int tid = threadIdx.x;
  for (int q = tid; q < AINC*HCD; q += 256) w1f[q / HCD][q % HCD] = w1[q];
  for (int q = tid; q < HCD*NHEAD; q += 256) w2f[q / NHEAD][q % NHEAD] = w2[q];
  if (tid < HCD) b1f[tid] = b1[tid];
  if (tid < NHEAD) b2f[tid] = b2[tid];
  int sub = tid >> 5, t = tid & 31;
  int e = blockIdx.x * 8 + sub;
  int d = e / EPN;
  int s = src[e];
  for (int k = t; k < SPHC; k += 32) {
    ain[sub][k]        = inv[(size_t)s * SPHC + k];
    ain[sub][SPHC + k] = inv[(size_t)d * SPHC + k];
  }
  float4 xs = Xw[s], xd = Xw[d];
  float dx = xs.x - xd.x, dy = xs.y - xd.y, dz = xs.z - xd.z;
  float dist = sqrtf(dx*dx + dy*dy + dz*dz);
  if (t < 16) {
    float mu = (20.0f / 15.0f) * (float)t;
    float zz = (dist - mu) / 1.25f;
    ain[sub][70 + t] = expf(-zz * zz);
  } else {
    int k = t - 16;
    float del = (float)(s - d);
    float fr = expf((float)(2 * (k & 7)) * -0.5756462732485115f);
    float a = del * fr;
    ain[sub][86 + k] = (k < 8) ? cosf(a) : sinf(a);
  }
  __syncthreads();
  float a = b1f[t];
  for (int k = 0; k < AINC; k++) a = fmaf(ain[sub][k], w1f[k][t], a);
  hbuf[sub][t] = a / (1.f + expf(-a));  // silu
  __syncthreads();
  if (tid < 64) {
    int e2 = tid >> 3, hh = tid & 7;
    float lg = b2f[hh];
    for (int c = 0; c < HCD; c++) lg = fmaf(hbuf[e2][c], w2f[c][hh], lg);
    logitO[(size_t)(blockIdx.x * 8 + e2) * NHEAD + hh] = lg;
  }
}

// ---- K4: per-node softmax, aggregate, SO3 output chain ----
__global__ __launch_bounds__(64) void node_kernel(const int* __restrict__ src,
                                                  const float* __restrict__ logit,
                                                  const float* __restrict__ V,
                                                  const float* __restrict__ wo,
                                                  const float* __restrict__ bo,
                                                  const float* __restrict__ wg,
                                                  const float* __restrict__ bg,
                                                  const float* __restrict__ wf,
                                                  const float* __restrict__ bfb,
                                                  const float* __restrict__ w_xca,
                                                  const float* __restrict__ w_gate,
                                                  const float* __restrict__ b_gate,
                                                  const float* __restrict__ w_bb,
                                                  const float* __restrict__ X,
                                                  const float* __restrict__ bbrel,
                                                  const int* __restrict__ nmask,
                                                  float* __restrict__ out) {
  const int n = blockIdx.x, t = threadIdx.x;
  __shared__ float alpha[EPN][NHEAD];
  __shared__ int slist[EPN];
  __shared__ float agg[LT][HVD];
  __shared__ float o0[LT][BBCC];
  __shared__ float ofin[LT][BBCC];
  __shared__ float gate[BBCC];
  if (t < EPN) slist[t] = src[(size_t)n * EPN + t];
  for (int q = t; q < EPN * NHEAD; q += 64) alpha[q / NHEAD][q % NHEAD] = logit[(size_t)n * 480 + q];
  __syncthreads();
  if (t < NHEAD) {
    float m = -1e30f;
    for (int e = 0; e < EPN; e++) m = fmaxf(m, alpha[e][t]);
    float Z = 0.f;
    for (int e = 0; e < EPN; e++) { float p = expf(alpha[e][t] - m); alpha[e][t] = p; Z += p; }
    float iz = 1.f / (Z + 1e-9f);
    for (int e = 0; e < EPN; e++) alpha[e][t] *= iz;
  }
  __syncthreads();
  {
    const int h = t >> 3;
    float acc[LT];
    #pragma unroll
    for (int l = 0; l < LT; l++) acc[l] = 0.f;
    for (int e = 0; e < EPN; e++) {
      const float* Vp = V + (size_t)slist[e] * (LT * HVD) + t;
      float a = alpha[e][h];
      #pragma unroll
      for (int l = 0; l < LT; l++) acc[l] = fmaf(a, Vp[l * HVD], acc[l]);
    }
    #pragma unroll
    for (int l = 0; l < LT; l++) agg[l][t] = acc[l];
  }
  __syncthreads();
  for (int idx = t; idx < LT * BBCC; idx += 64) {
    int l = idx >> 5, d = idx & 31;
    int li = (l == 0) ? 0 : (l < 4 ? 1 : 2);
    float a = (l == 0) ? bo[d] : 0.f;
    const float* w = wo + (size_t)li * HVD * BBCC;
    for (int c = 0; c < HVD; c++) a = fmaf(agg[l][c], w[c * BBCC + d], a);
    o0[l][d] = a;
  }
  __syncthreads();
  if (t < BBCC) {
    float a = bg[t];
    for (int c = 0; c < BBCC; c++) a = fmaf(o0[0][c], wg[c * BBCC + t], a);
    gate[t] = a / (1.f + expf(-a));
  }
  __syncthreads();
  for (int idx = t; idx < LT * BBCC; idx += 64) {
    int l = idx >> 5, d = idx & 31;
    int li = (l == 0) ? 0 : (l < 4 ? 1 : 2);
    float a = (l == 0) ? bfb[d] : 0.f;
    const float* w = wf + (size_t)li * BBCC * BBCC;
    for (int c = 0; c < BBCC; c++) a = fmaf(o0[l][c], w[c * BBCC + d], a);
    float r = o0[l][d] + a * gate[d];
    ofin[l][d] = r;
    out[49152 + (size_t)n * 288 + idx] = r;
  }
  __syncthreads();
  float a2 = b_gate[0];
  for (int c = 0; c < BBCC; c++) a2 = fmaf(ofin[0][c], w_gate[c], a2);
  float g2 = fmaxf(a2, 0.f) + log1pf(expf(-fabsf(a2)));
  bool noise = nmask[n] != 0;
  if (t < 3) {
    float a = 0.f;
    for (int d2 = 0; d2 < BBCC; d2++) a = fmaf(ofin[1 + t][d2], w_xca[32 + d2], a);
    float nx = X[n * 3 + t] + (noise ? a * g2 : 0.f);
    out[(size_t)n * 3 + t] = nx;
  }
  if (t < 9) {
    int b = t / 3, c = t % 3;
    float a = 0.f;
    for (int d2 = 0; d2 < BBCC; d2++) a = fmaf(ofin[1 + c][d2], w_bb[(32 + d2) * 3 + b], a);
    float nb = bbrel[(size_t)(n * 3 + b) * 3 + c] + (noise ? a : 0.f);
    out[12288 + (size_t)n * 9 + b * 3 + c] = nb;
  }
}

extern "C" void kernel_launch(void* const* d_in, const int* in_sizes, int n_in,
                              void* d_out, int out_size, void* d_ws, size_t ws_size,
                              hipStream_t stream) {
  (void)in_sizes; (void)n_in; (void)out_size;
  const float* X      = (const float*)d_in[0];
  const float* bbrel  = (const float*)d_in[1];
  const float* bbf    = (const float*)d_in[2];
  const int* batch    = (const int*)d_in[3];
  const int* xmask    = (const int*)d_in[4];
  const int* nmask    = (const int*)d_in[5];
  const float* w1     = (const float*)d_in[6];
  const float* b1     = (const float*)d_in[7];
  const float* w2     = (const float*)d_in[8];
  const float* b2     = (const float*)d_in[9];
  const float* wv     = (const float*)d_in[10];
  const float* bv     = (const float*)d_in[11];
  const float* wo     = (const float*)d_in[12];
  const float* bo     = (const float*)d_in[13];
  const float* wg     = (const float*)d_in[14];
  const float* bg     = (const float*)d_in[15];
  const float* wf     = (const float*)d_in[16];
  const float* bfb    = (const float*)d_in[17];
  const float* w_xca  = (const float*)d_in[18];
  const float* w_gate = (const float*)d_in[20];
  const float* b_gate = (const float*)d_in[21];
  const float* w_bb   = (const float*)d_in[22];

  if (ws_size < 18939904) return;
  char* ws = (char*)d_ws;
  float4*   Xw    = (float4*)(ws + 0);
  uint32_t* bmp   = (uint32_t*)(ws + 65536);
  float*    inv   = (float*)(ws + 81920);
  int*      srcl  = (int*)(ws + 655360);
  float*    logit = (float*)(ws + 1638400);
  float*    V     = (float*)(ws + 9502720);
  float*    out   = (float*)d_out;

  prep_kernel<<<NN / 256, 256, 0, stream>>>(X, batch, xmask, nmask, bbf, Xw, bmp, inv);
  select_kernel<<<NN, 256, 0, stream>>>(Xw, bmp, srcl);
  vmat_kernel<<<(NN * LT) / 4, 256, 0, stream>>>(bbf, bbrel, nmask, wv, bv, V);
  edge_kernel<<<NE / 8, 256, 0, stream>>>(srcl, Xw, inv, w1, b1, w2, b2, logit);
  node_kernel<<<NN, 64, 0, stream>>>(srcl, logit, V, wo, bo, wg, bg, wf, bfb,
                                     w_xca, w_gate, b_gate, w_bb, X, bbrel, nmask, out);
}

// Round 5
// 305.053 us; speedup vs baseline: 1.6508x; 1.2152x over previous
//
#include <hip/hip_runtime.h>
#include <hip/hip_bf16.h>
#include <stdint.h>

#define NN 4096
#define CS 2048           // chain size (NN / CHAINS)
#define KNN 20
#define LRK 40
#define EPN 60
#define NE (NN*EPN)
#define SPHC 35
#define BBCC 32
#define NHEAD 8
#define HVD 64
#define HCD 32
#define LT 9

#define INVAL_D2 0xFFFFFFFEu
#define CONSUMED 0xFFFFFFFFu

// ---- bit-exact replica of jax.random.gumbel(key(1), (4096,4096))[i,j] (up to logf rounding) ----
__device__ __forceinline__ float gumbel_f(int i, int j) {
  uint32_t c = ((uint32_t)(i & 2047) << 12) | (uint32_t)j;
  const uint32_t ks0 = 0u, ks1 = 1u, ks2 = 0x1BD11BDBu;
  uint32_t x0 = c + ks0;
  uint32_t x1 = (c + 0x800000u) + ks1;
#define TF_R(r) { x0 += x1; x1 = (x1 << (r)) | (x1 >> (32 - (r))); x1 ^= x0; }
  TF_R(13) TF_R(15) TF_R(26) TF_R(6)   x0 += ks1; x1 += ks2 + 1u;
  TF_R(17) TF_R(29) TF_R(16) TF_R(24)  x0 += ks2; x1 += ks0 + 2u;
  TF_R(13) TF_R(15) TF_R(26) TF_R(6)   x0 += ks0; x1 += ks1 + 3u;
  TF_R(17) TF_R(29) TF_R(16) TF_R(24)  x0 += ks1; x1 += ks2 + 4u;
  TF_R(13) TF_R(15) TF_R(26) TF_R(6)   x0 += ks2; x1 += ks0 + 5u;
#undef TF_R
  uint32_t b = (i >= 2048) ? x1 : x0;
  float u = __uint_as_float((b >> 9) | 0x3F800000u) - 1.0f;
  u = u + 1.17549435e-38f;
  return -logf(-logf(u));
}

// ---- P0: Xw=(x,y,z,|x|^2), batch/mask word ----
__global__ void prep_kernel(const float* __restrict__ X,
                            const int* __restrict__ batch,
                            const int* __restrict__ xmask,
                            float4* __restrict__ Xw, uint32_t* __restrict__ bm) {
#pragma clang fp contract(off)
  int n = blockIdx.x * blockDim.x + threadIdx.x;
  if (n >= NN) return;
  float x = X[n*3+0], y = X[n*3+1], z = X[n*3+2];
  float x2 = (x*x + y*y) + z*z;
  Xw[n] = make_float4(x, y, z, x2);
  bm[n] = ((uint32_t)batch[n] << 1) | (xmask[n] ? 1u : 0u);
}

// ---- P1: per-node projections Pn = inv@W1[0:35], Pd = inv@W1[35:70] + b1 ----
__global__ __launch_bounds__(256) void nodeproj_kernel(const float* __restrict__ bbf,
                                                       const int* __restrict__ nmask,
                                                       const float* __restrict__ w1,
                                                       const float* __restrict__ b1,
                                                       float* __restrict__ Pn,
                                                       float* __restrict__ Pd) {
  int tid = threadIdx.x;
  int t = tid & 31;
  int n = blockIdx.x * 8 + (tid >> 5);
  float bv_ = bbf[(size_t)n * (LT*BBCC) + t];   // bbf[n, l=0, t]
  float an = 0.f, ad = b1[t];
  #pragma unroll 8
  for (int c = 0; c < BBCC; c++) {
    float bc = __shfl(bv_, (tid & 32) + c, 64);
    an = fmaf(bc, w1[c * HCD + t], an);
    ad = fmaf(bc, w1[(SPHC + c) * HCD + t], ad);
  }
  float nm = nmask[n] ? 1.f : 0.f;
  an = fmaf(nm, w1[34 * HCD + t], an);
  ad = fmaf(nm, w1[69 * HCD + t], ad);
  Pn[n * HCD + t] = an;
  Pd[n * HCD + t] = ad;
}

// ---- exact k-th-smallest radix select + compaction ----
__device__ __forceinline__ void radix_select(uint32_t* val, uint32_t* hist,
                                             uint32_t* sh, uint32_t* eqpos,
                                             int* sel, int k, int base, int cb, int tid) {
  uint32_t vpart = 0, rk = (uint32_t)k;
  for (int shift = 24; shift >= 0; shift -= 8) {
    hist[tid] = 0;
    __syncthreads();
    #pragma unroll
    for (int q = 0; q < 8; q++) {
      uint32_t key = val[tid + (q << 8)];
      if ((((uint64_t)(key ^ vpart)) >> (shift + 8)) == 0)
        atomicAdd(&hist[(key >> shift) & 255u], 1u);
    }
    __syncthreads();
    if (tid < 64) {
      uint32_t c0 = hist[tid*4+0], c1 = hist[tid*4+1], c2 = hist[tid*4+2], c3 = hist[tid*4+3];
      uint32_t s = c0 + c1 + c2 + c3;
      uint32_t cum = s;
      #pragma unroll
      for (int off = 1; off < 64; off <<= 1) {
        uint32_t o = __shfl_up(cum, off, 64);
        if (tid >= off) cum += o;
      }
      uint32_t cumprev = cum - s;
      if (rk > cumprev && rk <= cum) {
        uint32_t r = rk - cumprev, dsel, sub;
        if (r <= c0)            { dsel = 0; sub = 0; }
        else if (r <= c0+c1)    { dsel = 1; sub = c0; }
        else if (r <= c0+c1+c2) { dsel = 2; sub = c0 + c1; }
        else                    { dsel = 3; sub = c0 + c1 + c2; }
        sh[0] = tid*4u + dsel;
        sh[1] = r - sub;
      }
    }
    __syncthreads();
    vpart |= (sh[0] << shift);
    rk = sh[1];
  }
  const uint32_t vstar = vpart;
  if (tid == 0) { sh[2] = 0; sh[3] = 0; }
  __syncthreads();
  #pragma unroll
  for (int q = 0; q < 8; q++) {
    int pos = tid + (q << 8);
    uint32_t key = val[pos];
    if (key < vstar) {
      uint32_t slot = atomicAdd(&sh[2], 1u);
      sel[base + slot] = cb + pos;
    } else if (key == vstar) {
      uint32_t t2 = atomicAdd(&sh[3], 1u);
      if (t2 < 64) eqpos[t2] = (uint32_t)pos;
    }
  }
  __syncthreads();
  if (tid == 0) {
    int have = (int)sh[2];
    int m = (int)sh[3]; if (m > 64) m = 64;
    for (int a = 1; a < m; a++) {
      uint32_t p = eqpos[a]; int b = a - 1;
      while (b >= 0 && eqpos[b] > p) { eqpos[b+1] = eqpos[b]; b--; }
      eqpos[b+1] = p;
    }
    for (int a = 0; a < m && have < k; a++) sel[base + have++] = cb + (int)eqpos[a];
  }
  __syncthreads();
}

// ---- K1: per-row knn20 + gumbel-lr40 via chain-restricted radix select ----
__global__ __launch_bounds__(256) void select_kernel(const float4* __restrict__ Xw,
                                                     const uint32_t* __restrict__ bm,
                                                     int* __restrict__ srcO) {
#pragma clang fp contract(off)
  __shared__ uint32_t val[CS];
  __shared__ uint32_t hist[256];
  __shared__ uint32_t sh[4];
  __shared__ uint32_t eqpos[64];
  __shared__ int sel[EPN];
  const int i = blockIdx.x, tid = threadIdx.x;
  const uint32_t bmi = bm[i];

  if (bmi & 1u) {
    if (tid < KNN) srcO[(size_t)i * EPN + tid] = tid;
    else if (tid < EPN) srcO[(size_t)i * EPN + tid] = tid - KNN;
    return;
  }
  const int cb = (int)(bmi >> 1) * CS;
  const float4 xi = Xw[i];

  #pragma unroll
  for (int q = 0; q < 8; q++) {
    int pos = tid + (q << 8);
    int j = cb + pos;
    float4 xj = Xw[j];
    uint32_t bmj = bm[j];
    bool inval = ((bmj & 1u) != 0u) || (j == i);
    float dot = xi.x*xj.x + xi.y*xj.y + xi.z*xj.z;
    float d2r = (xi.w + xj.w) - 2.0f*dot;
    float d2 = d2r > 0.0f ? d2r : 0.0f;
    val[pos] = inval ? INVAL_D2 : __float_as_uint(d2);
  }
  __syncthreads();

  radix_select(val, hist, sh, eqpos, sel, KNN, 0, cb, tid);

  if (tid < KNN) val[sel[tid] - cb] = CONSUMED;
  __syncthreads();

  #pragma unroll
  for (int q = 0; q < 8; q++) {
    int pos = tid + (q << 8);
    uint32_t v = val[pos];
    uint32_t skey;
    if (v >= INVAL_D2) skey = CONSUMED;
    else {
      float d2 = __uint_as_float(v);
      float sc = -1.5f * logf(d2 + 1e-6f) + gumbel_f(i, cb + pos);
      uint32_t u = __float_as_uint(sc);
      uint32_t fl = (u & 0x80000000u) ? ~u : (u | 0x80000000u);
      skey = ~fl;
    }
    val[pos] = skey;
  }
  __syncthreads();

  radix_select(val, hist, sh, eqpos, sel, LRK, KNN, cb, tid);

  if (tid < EPN) srcO[(size_t)i * EPN + tid] = sel[tid];
}

// ---- K2: V[n,l,:] = so3_linear(node, wv, bv) ----
__global__ __launch_bounds__(256) void vmat_kernel(const float* __restrict__ bbf,
                                                   const float* __restrict__ bbrel,
                                                   const int* __restrict__ nmask,
                                                   const float* __restrict__ wv,
                                                   const float* __restrict__ bv,
                                                   float* __restrict__ V) {
  int row = blockIdx.x * 4 + (threadIdx.x >> 6);
  int d = threadIdx.x & 63;
  if (row >= NN * LT) return;
  int n = row / LT, l = row % LT;
  int li = (l == 0) ? 0 : (l < 4 ? 1 : 2);
  const float* w = wv + (size_t)li * SPHC * HVD;
  float acc = (l == 0) ? bv[d] : 0.f;
  const float* nb = bbf + (size_t)(n*LT + l) * BBCC;
  for (int c = 0; c < BBCC; c++) acc = fmaf(nb[c], w[c*HVD + d], acc);
  if (l >= 1 && l < 4) {
    for (int b = 0; b < 3; b++)
      acc = fmaf(bbrel[(size_t)(n*3 + b)*3 + (l-1)], w[(32+b)*HVD + d], acc);
  }
  if (l == 0) acc = fmaf(nmask[n] ? 1.f : 0.f, w[34*HVD + d], acc);
  V[(size_t)row * HVD + d] = acc;
}

// ---- K3: edge MLP -> logits, using per-node projections ----
__global__ __launch_bounds__(256) void edge_kernel(const int* __restrict__ src,
                                                   const float4* __restrict__ Xw,
                                                   const float* __restrict__ Pn,
                                                   const float* __restrict__ Pd,
                                                   const float* __restrict__ w1,
                                                   const float* __restrict__ w2,
                                                   const float* __restrict__ b2,
                                                   float* __restrict__ logitO) {
  __shared__ float w1cf[BBCC][HCD];   // W1 rows 70..101 (edge_feat block)
  __shared__ float w2f[HCD][NHEAD];
  __shared__ float b2f[NHEAD];
  __shared__ float ef[8][BBCC];
  __shared__ float hbuf[8][HCD];
  int tid = threadIdx.x;
  for (int q = tid; q < BBCC*HCD; q += 256) w1cf[q >> 5][q & 31] = w1[70*HCD + q];
  if (tid < HCD*NHEAD) w2f[tid >> 3][tid & 7] = w2[tid];
  if (tid < NHEAD) b2f[tid] = b2[tid];
  int sub = tid >> 5, t = tid & 31;
  int e = blockIdx.x * 8 + sub;
  int d = e / EPN;
  int s = src[e];
  float4 xs = Xw[s], xd = Xw[d];
  float dx = xs.x - xd.x, dy = xs.y - xd.y, dz = xs.z - xd.z;
  float dist = sqrtf(dx*dx + dy*dy + dz*dz);
  if (t < 16) {
    float mu = (20.0f / 15.0f) * (float)t;
    float zz = (dist - mu) / 1.25f;
    ef[sub][t] = expf(-zz * zz);
  } else {
    int k = t - 16;
    float del = (float)(s - d);
    float fr = expf((float)(2 * (k & 7)) * -0.5756462732485115f);
    float a = del * fr;
    ef[sub][t] = (k < 8) ? cosf(a) : sinf(a);
  }
  __syncthreads();
  float a = Pn[s * HCD + t] + Pd[d * HCD + t];
  #pragma unroll
  for (int k = 0; k < BBCC; k++) a = fmaf(ef[sub][k], w1cf[k][t], a);
  hbuf[sub][t] = a / (1.f + expf(-a));  // silu
  __syncthreads();
  if (tid < 64) {
    int e2 = tid >> 3, hh = tid & 7;
    float lg = b2f[hh];
    #pragma unroll
    for (int c = 0; c < HCD; c++) lg = fmaf(hbuf[e2][c], w2f[c][hh], lg);
    logitO[(size_t)(blockIdx.x * 8 + e2) * NHEAD + hh] = lg;
  }
}

// ---- K4: per-node softmax, aggregate, SO3 output chain ----
__global__ __launch_bounds__(64) void node_kernel(const int* __restrict__ src,
                                                  const float* __restrict__ logit,
                                                  const float* __restrict__ V,
                                                  const float* __restrict__ wo,
                                                  const float* __restrict__ bo,
                                                  const float* __restrict__ wg,
                                                  const float* __restrict__ bg,
                                                  const float* __restrict__ wf,
                                                  const float* __restrict__ bfb,
                                                  const float* __restrict__ w_xca,
                                                  const float* __restrict__ w_gate,
                                                  const float* __restrict__ b_gate,
                                                  const float* __restrict__ w_bb,
                                                  const float* __restrict__ X,
                                                  const float* __restrict__ bbrel,
                                                  const int* __restrict__ nmask,
                                                  float* __restrict__ out) {
  const int n = blockIdx.x, t = threadIdx.x;
  __shared__ float alpha[EPN][NHEAD];
  __shared__ int slist[EPN];
  __shared__ float agg[LT][HVD];
  __shared__ float o0[LT][BBCC];
  __shared__ float ofin[LT][BBCC];
  __shared__ float gate[BBCC];
  if (t < EPN) slist[t] = src[(size_t)n * EPN + t];
  for (int q = t; q < EPN * NHEAD; q += 64) alpha[q / NHEAD][q % NHEAD] = logit[(size_t)n * 480 + q];
  __syncthreads();
  if (t < NHEAD) {
    float m = -1e30f;
    for (int e = 0; e < EPN; e++) m = fmaxf(m, alpha[e][t]);
    float Z = 0.f;
    for (int e = 0; e < EPN; e++) { float p = expf(alpha[e][t] - m); alpha[e][t] = p; Z += p; }
    float iz = 1.f / (Z + 1e-9f);
    for (int e = 0; e < EPN; e++) alpha[e][t] *= iz;
  }
  __syncthreads();
  {
    const int h = t >> 3;
    float acc[LT];
    #pragma unroll
    for (int l = 0; l < LT; l++) acc[l] = 0.f;
    for (int e = 0; e < EPN; e++) {
      const float* Vp = V + (size_t)slist[e] * (LT * HVD) + t;
      float a = alpha[e][h];
      #pragma unroll
      for (int l = 0; l < LT; l++) acc[l] = fmaf(a, Vp[l * HVD], acc[l]);
    }
    #pragma unroll
    for (int l = 0; l < LT; l++) agg[l][t] = acc[l];
  }
  __syncthreads();
  for (int idx = t; idx < LT * BBCC; idx += 64) {
    int l = idx >> 5, d = idx & 31;
    int li = (l == 0) ? 0 : (l < 4 ? 1 : 2);
    float a = (l == 0) ? bo[d] : 0.f;
    const float* w = wo + (size_t)li * HVD * BBCC;
    for (int c = 0; c < HVD; c++) a = fmaf(agg[l][c], w[c * BBCC + d], a);
    o0[l][d] = a;
  }
  __syncthreads();
  if (t < BBCC) {
    float a = bg[t];
    for (int c = 0; c < BBCC; c++) a = fmaf(o0[0][c], wg[c * BBCC + t], a);
    gate[t] = a / (1.f + expf(-a));
  }
  __syncthreads();
  for (int idx = t; idx < LT * BBCC; idx += 64) {
    int l = idx >> 5, d = idx & 31;
    int li = (l == 0) ? 0 : (l < 4 ? 1 : 2);
    float a = (l == 0) ? bfb[d] : 0.f;
    const float* w = wf + (size_t)li * BBCC * BBCC;
    for (int c = 0; c < BBCC; c++) a = fmaf(o0[l][c], w[c * BBCC + d], a);
    float r = o0[l][d] + a * gate[d];
    ofin[l][d] = r;
    out[49152 + (size_t)n * 288 + idx] = r;
  }
  __syncthreads();
  float a2 = b_gate[0];
  for (int c = 0; c < BBCC; c++) a2 = fmaf(ofin[0][c], w_gate[c], a2);
  float g2 = fmaxf(a2, 0.f) + log1pf(expf(-fabsf(a2)));
  bool noise = nmask[n] != 0;
  if (t < 3) {
    float a = 0.f;
    for (int d2 = 0; d2 < BBCC; d2++) a = fmaf(ofin[1 + t][d2], w_xca[32 + d2], a);
    float nx = X[n * 3 + t] + (noise ? a * g2 : 0.f);
    out[(size_t)n * 3 + t] = nx;
  }
  if (t < 9) {
    int b = t / 3, c = t % 3;
    float a = 0.f;
    for (int d2 = 0; d2 < BBCC; d2++) a = fmaf(ofin[1 + c][d2], w_bb[(32 + d2) * 3 + b], a);
    float nb = bbrel[(size_t)(n * 3 + b) * 3 + c] + (noise ? a : 0.f);
    out[12288 + (size_t)n * 9 + b * 3 + c] = nb;
  }
}

extern "C" void kernel_launch(void* const* d_in, const int* in_sizes, int n_in,
                              void* d_out, int out_size, void* d_ws, size_t ws_size,
                              hipStream_t stream) {
  (void)in_sizes; (void)n_in; (void)out_size;
  const float* X      = (const float*)d_in[0];
  const float* bbrel  = (const float*)d_in[1];
  const float* bbf    = (const float*)d_in[2];
  const int* batch    = (const int*)d_in[3];
  const int* xmask    = (const int*)d_in[4];
  const int* nmask    = (const int*)d_in[5];
  const float* w1     = (const float*)d_in[6];
  const float* b1     = (const float*)d_in[7];
  const float* w2     = (const float*)d_in[8];
  const float* b2     = (const float*)d_in[9];
  const float* wv     = (const float*)d_in[10];
  const float* bv     = (const float*)d_in[11];
  const float* wo     = (const float*)d_in[12];
  const float* bo     = (const float*)d_in[13];
  const float* wg     = (const float*)d_in[14];
  const float* bg     = (const float*)d_in[15];
  const float* wf     = (const float*)d_in[16];
  const float* bfb    = (const float*)d_in[17];
  const float* w_xca  = (const float*)d_in[18];
  const float* w_gate = (const float*)d_in[20];
  const float* b_gate = (const float*)d_in[21];
  const float* w_bb   = (const float*)d_in[22];

  if (ws_size < 18939904) return;
  char* ws = (char*)d_ws;
  // lifetimes: bmp/srcl/logit/V persistent; Pn/Pd/Xw overlapped INSIDE V's
  // region (dead before vmat writes V; vmat launched after edge).
  uint32_t* bmp   = (uint32_t*)(ws + 0);          //  16KB
  int*      srcl  = (int*)(ws + 16384);           // 960KB
  float*    logit = (float*)(ws + 999424);        // 7.5MB
  float*    V     = (float*)(ws + 8863744);       // 9.0MB -> end 18300928
  float*    Pn    = (float*)(ws + 8863744);       // 512KB (overlaps V)
  float*    Pd    = (float*)(ws + 9388032);       // 512KB (overlaps V)
  float4*   Xw    = (float4*)(ws + 9912320);      //  64KB (overlaps V)
  float*    out   = (float*)d_out;

  prep_kernel<<<NN / 256, 256, 0, stream>>>(X, batch, xmask, Xw, bmp);
  nodeproj_kernel<<<NN / 8, 256, 0, stream>>>(bbf, nmask, w1, b1, Pn, Pd);
  select_kernel<<<NN, 256, 0, stream>>>(Xw, bmp, srcl);
  edge_kernel<<<NE / 8, 256, 0, stream>>>(srcl, Xw, Pn, Pd, w1, w2, b2, logit);
  vmat_kernel<<<(NN * LT) / 4, 256, 0, stream>>>(bbf, bbrel, nmask, wv, bv, V);
  node_kernel<<<NN, 64, 0, stream>>>(srcl, logit, V, wo, bo, wg, bg, wf, bfb,
                                     w_xca, w_gate, b_gate, w_bb, X, bbrel, nmask, out);
}

// Round 6
// 277.421 us; speedup vs baseline: 1.8152x; 1.0996x over previous
//
#include <hip/hip_runtime.h>
#include <hip/hip_bf16.h>
#include <stdint.h>

#define NN 4096
#define CS 2048           // chain size (NN / CHAINS)
#define KNN 20
#define LRK 40
#define EPN 60
#define NE (NN*EPN)
#define SPHC 35
#define BBCC 32
#define NHEAD 8
#define HVD 64
#define HCD 32
#define LT 9
#define MAXC 384          // candidate cap for the k-th bucket (tail bucket: ~tens)

#define INVAL_D2 0xFFFFFFFEu
#define CONSUMED 0xFFFFFFFFu

// ---- threefry2x32(key=[0,1]) -> -log(u) for jax uniform draw at (i,j) ----
// Bit-exact u; one logf (order-equivalent score trick applied by caller).
__device__ __forceinline__ float neglogu_f(int i, int j) {
  uint32_t c = ((uint32_t)(i & 2047) << 12) | (uint32_t)j;
  const uint32_t ks0 = 0u, ks1 = 1u, ks2 = 0x1BD11BDBu;
  uint32_t x0 = c + ks0;
  uint32_t x1 = (c + 0x800000u) + ks1;
#define TF_R(r) { x0 += x1; x1 = (x1 << (r)) | (x1 >> (32 - (r))); x1 ^= x0; }
  TF_R(13) TF_R(15) TF_R(26) TF_R(6)   x0 += ks1; x1 += ks2 + 1u;
  TF_R(17) TF_R(29) TF_R(16) TF_R(24)  x0 += ks2; x1 += ks0 + 2u;
  TF_R(13) TF_R(15) TF_R(26) TF_R(6)   x0 += ks0; x1 += ks1 + 3u;
  TF_R(17) TF_R(29) TF_R(16) TF_R(24)  x0 += ks1; x1 += ks2 + 4u;
  TF_R(13) TF_R(15) TF_R(26) TF_R(6)   x0 += ks2; x1 += ks0 + 5u;
#undef TF_R
  uint32_t b = (i >= 2048) ? x1 : x0;
  float u = __uint_as_float((b >> 9) | 0x3F800000u) - 1.0f;
  u = u + 1.17549435e-38f;
  return -logf(u);         // > 0 always (u < 1)
}

// ---- P0: Xw=(x,y,z,|x|^2), batch/mask word ----
__global__ void prep_kernel(const float* __restrict__ X,
                            const int* __restrict__ batch,
                            const int* __restrict__ xmask,
                            float4* __restrict__ Xw, uint32_t* __restrict__ bm) {
#pragma clang fp contract(off)
  int n = blockIdx.x * blockDim.x + threadIdx.x;
  if (n >= NN) return;
  float x = X[n*3+0], y = X[n*3+1], z = X[n*3+2];
  float x2 = (x*x + y*y) + z*z;
  Xw[n] = make_float4(x, y, z, x2);
  bm[n] = ((uint32_t)batch[n] << 1) | (xmask[n] ? 1u : 0u);
}

// ---- P1: per-node projections Pn = inv@W1[0:35], Pd = inv@W1[35:70] + b1 ----
__global__ __launch_bounds__(256) void nodeproj_kernel(const float* __restrict__ bbf,
                                                       const int* __restrict__ nmask,
                                                       const float* __restrict__ w1,
                                                       const float* __restrict__ b1,
                                                       float* __restrict__ Pn,
                                                       float* __restrict__ Pd) {
  int tid = threadIdx.x;
  int t = tid & 31;
  int n = blockIdx.x * 8 + (tid >> 5);
  float bv_ = bbf[(size_t)n * (LT*BBCC) + t];
  float an = 0.f, ad = b1[t];
  #pragma unroll 8
  for (int c = 0; c < BBCC; c++) {
    float bc = __shfl(bv_, (tid & 32) + c, 64);
    an = fmaf(bc, w1[c * HCD + t], an);
    ad = fmaf(bc, w1[(SPHC + c) * HCD + t], ad);
  }
  float nm = nmask[n] ? 1.f : 0.f;
  an = fmaf(nm, w1[34 * HCD + t], an);
  ad = fmaf(nm, w1[69 * HCD + t], ad);
  Pn[n * HCD + t] = an;
  Pd[n * HCD + t] = ad;
}

// ---- 2-level (11-bit bucket) exact k-th-smallest select + compaction ----
// Set selected = {k smallest (key, pos) lex pairs}; sel[base..base+k) = cb+pos.
__device__ __forceinline__ void sel2l(uint32_t* val, uint32_t* hist2,
                                      uint32_t* candk, uint32_t* candp,
                                      uint32_t* sh, int* sel,
                                      int k, int base, int cb, int tid) {
  {
    uint4* h4 = (uint4*)hist2;
    uint4 z; z.x = 0; z.y = 0; z.z = 0; z.w = 0;
    h4[tid] = z; h4[tid + 256] = z;
  }
  if (tid == 0) { sh[2] = 0; sh[3] = 0; }
  __syncthreads();
  #pragma unroll
  for (int q = 0; q < 8; q++) {
    uint32_t key = val[tid + (q << 8)];
    atomicAdd(&hist2[key >> 21], 1u);
  }
  __syncthreads();
  // scan: thread t owns buckets [8t, 8t+8)
  uint32_t h[8], s = 0;
  #pragma unroll
  for (int q = 0; q < 8; q++) { h[q] = hist2[tid*8 + q]; s += h[q]; }
  uint32_t cum = s;
  #pragma unroll
  for (int off = 1; off < 64; off <<= 1) {
    uint32_t o = __shfl_up(cum, off, 64);
    if ((tid & 63) >= off) cum += o;
  }
  if ((tid & 63) == 63) sh[8 + (tid >> 6)] = cum;
  __syncthreads();
  uint32_t woff = 0;
  for (int w = 0; w < (tid >> 6); w++) woff += sh[8 + w];
  uint32_t cumAll = cum + woff;
  uint32_t cumBefore = cumAll - s;
  uint32_t rk = (uint32_t)k;
  if (rk > cumBefore && rk <= cumAll) {       // exactly one thread
    uint32_t rloc = rk - cumBefore, lp = 0;
    bool done = false;
    #pragma unroll
    for (int q = 0; q < 8; q++) {
      lp += h[q];
      if (!done && rloc <= lp) { sh[0] = (uint32_t)(tid*8 + q); sh[1] = rloc - (lp - h[q]); done = true; }
    }
  }
  __syncthreads();
  const uint32_t B = sh[0], r = sh[1];
  #pragma unroll
  for (int q = 0; q < 8; q++) {
    int pos = tid + (q << 8);
    uint32_t key = val[pos];
    if ((key >> 21) == B) {
      uint32_t idx = atomicAdd(&sh[2], 1u);
      if (idx < MAXC) { candk[idx] = key; candp[idx] = (uint32_t)pos; }
    }
  }
  __syncthreads();
  int m = (int)sh[2]; if (m > MAXC) m = MAXC;
  if (tid < 64) {                              // wave0: exact r-th by (key,pos) lex
    for (int ci = tid; ci < m; ci += 64) {
      unsigned long long k64 = ((unsigned long long)candk[ci] << 32) | candp[ci];
      uint32_t rank = 0;
      for (int j = 0; j < m; j++) {
        unsigned long long o = ((unsigned long long)candk[j] << 32) | candp[j];
        rank += (o < k64) ? 1u : 0u;
      }
      if (rank == r - 1) { sh[0] = candk[ci]; sh[1] = candp[ci]; }
    }
  }
  __syncthreads();
  const uint32_t vstar = sh[0], istar = sh[1];
  #pragma unroll
  for (int q = 0; q < 8; q++) {
    int pos = tid + (q << 8);
    uint32_t key = val[pos];
    if (key < vstar || (key == vstar && (uint32_t)pos <= istar)) {
      uint32_t slot = atomicAdd(&sh[3], 1u);
      sel[base + (int)slot] = cb + pos;
    }
  }
  __syncthreads();
}

// ---- K1: per-row knn20 + gumbel-lr40 via chain-restricted 2-level select ----
__global__ __launch_bounds__(256) void select_kernel(const float4* __restrict__ Xw,
                                                     const uint32_t* __restrict__ bm,
                                                     int* __restrict__ srcO) {
#pragma clang fp contract(off)
  __shared__ uint32_t val[CS];       // 8KB
  __shared__ uint32_t hist2[2048];   // 8KB
  __shared__ uint32_t candk[MAXC];
  __shared__ uint32_t candp[MAXC];
  __shared__ uint32_t sh[12];
  __shared__ int sel[EPN];
  const int i = blockIdx.x, tid = threadIdx.x;
  const uint32_t bmi = bm[i];

  if (bmi & 1u) {                    // x_masked row: all tie at -BIG -> indices 0..k-1
    if (tid < KNN) srcO[(size_t)i * EPN + tid] = tid;
    else if (tid < EPN) srcO[(size_t)i * EPN + tid] = tid - KNN;
    return;
  }
  const int cb = (int)(bmi >> 1) * CS;
  const float4 xi = Xw[i];

  #pragma unroll
  for (int q = 0; q < 8; q++) {
    int pos = tid + (q << 8);
    int j = cb + pos;
    float4 xj = Xw[j];
    uint32_t bmj = bm[j];
    bool inval = ((bmj & 1u) != 0u) || (j == i);
    float dot = xi.x*xj.x + xi.y*xj.y + xi.z*xj.z;
    float d2r = (xi.w + xj.w) - 2.0f*dot;
    float d2 = d2r > 0.0f ? d2r : 0.0f;
    val[pos] = inval ? INVAL_D2 : __float_as_uint(d2);
  }
  __syncthreads();

  sel2l(val, hist2, candk, candp, sh, sel, KNN, 0, cb, tid);

  if (tid < KNN) val[sel[tid] - cb] = CONSUMED;
  __syncthreads();

  // descending score == ascending w = (d2+1e-6)^1.5 * (-log u)   [w > 0]
  #pragma unroll
  for (int q = 0; q < 8; q++) {
    int pos = tid + (q << 8);
    uint32_t v = val[pos];
    uint32_t skey;
    if (v >= INVAL_D2) skey = CONSUMED;
    else {
      float d2p = __uint_as_float(v) + 1e-6f;
      float w = d2p * sqrtf(d2p) * neglogu_f(i, cb + pos);
      skey = __float_as_uint(w);
    }
    val[pos] = skey;
  }
  __syncthreads();

  sel2l(val, hist2, candk, candp, sh, sel, LRK, KNN, cb, tid);

  if (tid < EPN) srcO[(size_t)i * EPN + tid] = sel[tid];
}

// ---- K2: V[n,l,:] = so3_linear(node, wv, bv) ----
__global__ __launch_bounds__(256) void vmat_kernel(const float* __restrict__ bbf,
                                                   const float* __restrict__ bbrel,
                                                   const int* __restrict__ nmask,
                                                   const float* __restrict__ wv,
                                                   const float* __restrict__ bv,
                                                   float* __restrict__ V) {
  int row = blockIdx.x * 4 + (threadIdx.x >> 6);
  int d = threadIdx.x & 63;
  if (row >= NN * LT) return;
  int n = row / LT, l = row % LT;
  int li = (l == 0) ? 0 : (l < 4 ? 1 : 2);
  const float* w = wv + (size_t)li * SPHC * HVD;
  float acc = (l == 0) ? bv[d] : 0.f;
  const float* nb = bbf + (size_t)(n*LT + l) * BBCC;
  for (int c = 0; c < BBCC; c++) acc = fmaf(nb[c], w[c*HVD + d], acc);
  if (l >= 1 && l < 4) {
    for (int b = 0; b < 3; b++)
      acc = fmaf(bbrel[(size_t)(n*3 + b)*3 + (l-1)], w[(32+b)*HVD + d], acc);
  }
  if (l == 0) acc = fmaf(nmask[n] ? 1.f : 0.f, w[34*HVD + d], acc);
  V[(size_t)row * HVD + d] = acc;
}

// ---- K3: edge MLP -> logits, using per-node projections ----
__global__ __launch_bounds__(256) void edge_kernel(const int* __restrict__ src,
                                                   const float4* __restrict__ Xw,
                                                   const float* __restrict__ Pn,
                                                   const float* __restrict__ Pd,
                                                   const float* __restrict__ w1,
                                                   const float* __restrict__ w2,
                                                   const float* __restrict__ b2,
                                                   float* __restrict__ logitO) {
  __shared__ float w1cf[BBCC][HCD];
  __shared__ float w2f[HCD][NHEAD];
  __shared__ float b2f[NHEAD];
  __shared__ float ef[8][BBCC];
  __shared__ float hbuf[8][HCD];
  int tid = threadIdx.x;
  for (int q = tid; q < BBCC*HCD; q += 256) w1cf[q >> 5][q & 31] = w1[70*HCD + q];
  if (tid < HCD*NHEAD) w2f[tid >> 3][tid & 7] = w2[tid];
  if (tid < NHEAD) b2f[tid] = b2[tid];
  int sub = tid >> 5, t = tid & 31;
  int e = blockIdx.x * 8 + sub;
  int d = e / EPN;
  int s = src[e];
  float4 xs = Xw[s], xd = Xw[d];
  float dx = xs.x - xd.x, dy = xs.y - xd.y, dz = xs.z - xd.z;
  float dist = sqrtf(dx*dx + dy*dy + dz*dz);
  if (t < 16) {
    float mu = (20.0f / 15.0f) * (float)t;
    float zz = (dist - mu) / 1.25f;
    ef[sub][t] = expf(-zz * zz);
  } else {
    int k = t - 16;
    float del = (float)(s - d);
    float fr = expf((float)(2 * (k & 7)) * -0.5756462732485115f);
    float a = del * fr;
    ef[sub][t] = (k < 8) ? cosf(a) : sinf(a);
  }
  __syncthreads();
  float a = Pn[s * HCD + t] + Pd[d * HCD + t];
  #pragma unroll
  for (int k = 0; k < BBCC; k++) a = fmaf(ef[sub][k], w1cf[k][t], a);
  hbuf[sub][t] = a / (1.f + expf(-a));  // silu
  __syncthreads();
  if (tid < 64) {
    int e2 = tid >> 3, hh = tid & 7;
    float lg = b2f[hh];
    #pragma unroll
    for (int c = 0; c < HCD; c++) lg = fmaf(hbuf[e2][c], w2f[c][hh], lg);
    logitO[(size_t)(blockIdx.x * 8 + e2) * NHEAD + hh] = lg;
  }
}

// ---- K4: per-node softmax, aggregate, SO3 output chain ----
__global__ __launch_bounds__(64) void node_kernel(const int* __restrict__ src,
                                                  const float* __restrict__ logit,
                                                  const float* __restrict__ V,
                                                  const float* __restrict__ wo,
                                                  const float* __restrict__ bo,
                                                  const float* __restrict__ wg,
                                                  const float* __restrict__ bg,
                                                  const float* __restrict__ wf,
                                                  const float* __restrict__ bfb,
                                                  const float* __restrict__ w_xca,
                                                  const float* __restrict__ w_gate,
                                                  const float* __restrict__ b_gate,
                                                  const float* __restrict__ w_bb,
                                                  const float* __restrict__ X,
                                                  const float* __restrict__ bbrel,
                                                  const int* __restrict__ nmask,
                                                  float* __restrict__ out) {
  const int n = blockIdx.x, t = threadIdx.x;
  __shared__ float alpha[EPN][NHEAD];
  __shared__ int slist[EPN];
  __shared__ float agg[LT][HVD];
  __shared__ float o0[LT][BBCC];
  __shared__ float ofin[LT][BBCC];
  __shared__ float gate[BBCC];
  if (t < EPN) slist[t] = src[(size_t)n * EPN + t];
  for (int q = t; q < EPN * NHEAD; q += 64) alpha[q / NHEAD][q % NHEAD] = logit[(size_t)n * 480 + q];
  __syncthreads();
  if (t < NHEAD) {
    float m = -1e30f;
    for (int e = 0; e < EPN; e++) m = fmaxf(m, alpha[e][t]);
    float Z = 0.f;
    for (int e = 0; e < EPN; e++) { float p = expf(alpha[e][t] - m); alpha[e][t] = p; Z += p; }
    float iz = 1.f / (Z + 1e-9f);
    for (int e = 0; e < EPN; e++) alpha[e][t] *= iz;
  }
  __syncthreads();
  {
    const int h = t >> 3;
    float acc[LT];
    #pragma unroll
    for (int l = 0; l < LT; l++) acc[l] = 0.f;
    for (int e = 0; e < EPN; e++) {
      const float* Vp = V + (size_t)slist[e] * (LT * HVD) + t;
      float a = alpha[e][h];
      #pragma unroll
      for (int l = 0; l < LT; l++) acc[l] = fmaf(a, Vp[l * HVD], acc[l]);
    }
    #pragma unroll
    for (int l = 0; l < LT; l++) agg[l][t] = acc[l];
  }
  __syncthreads();
  for (int idx = t; idx < LT * BBCC; idx += 64) {
    int l = idx >> 5, d = idx & 31;
    int li = (l == 0) ? 0 : (l < 4 ? 1 : 2);
    float a = (l == 0) ? bo[d] : 0.f;
    const float* w = wo + (size_t)li * HVD * BBCC;
    for (int c = 0; c < HVD; c++) a = fmaf(agg[l][c], w[c * BBCC + d], a);
    o0[l][d] = a;
  }
  __syncthreads();
  if (t < BBCC) {
    float a = bg[t];
    for (int c = 0; c < BBCC; c++) a = fmaf(o0[0][c], wg[c * BBCC + t], a);
    gate[t] = a / (1.f + expf(-a));
  }
  __syncthreads();
  for (int idx = t; idx < LT * BBCC; idx += 64) {
    int l = idx >> 5, d = idx & 31;
    int li = (l == 0) ? 0 : (l < 4 ? 1 : 2);
    float a = (l == 0) ? bfb[d] : 0.f;
    const float* w = wf + (size_t)li * BBCC * BBCC;
    for (int c = 0; c < BBCC; c++) a = fmaf(o0[l][c], w[c * BBCC + d], a);
    float r = o0[l][d] + a * gate[d];
    ofin[l][d] = r;
    out[49152 + (size_t)n * 288 + idx] = r;
  }
  __syncthreads();
  float a2 = b_gate[0];
  for (int c = 0; c < BBCC; c++) a2 = fmaf(ofin[0][c], w_gate[c], a2);
  float g2 = fmaxf(a2, 0.f) + log1pf(expf(-fabsf(a2)));
  bool noise = nmask[n] != 0;
  if (t < 3) {
    float a = 0.f;
    for (int d2 = 0; d2 < BBCC; d2++) a = fmaf(ofin[1 + t][d2], w_xca[32 + d2], a);
    float nx = X[n * 3 + t] + (noise ? a * g2 : 0.f);
    out[(size_t)n * 3 + t] = nx;
  }
  if (t < 9) {
    int b = t / 3, c = t % 3;
    float a = 0.f;
    for (int d2 = 0; d2 < BBCC; d2++) a = fmaf(ofin[1 + c][d2], w_bb[(32 + d2) * 3 + b], a);
    float nb = bbrel[(size_t)(n * 3 + b) * 3 + c] + (noise ? a : 0.f);
    out[12288 + (size_t)n * 9 + b * 3 + c] = nb;
  }
}

extern "C" void kernel_launch(void* const* d_in, const int* in_sizes, int n_in,
                              void* d_out, int out_size, void* d_ws, size_t ws_size,
                              hipStream_t stream) {
  (void)in_sizes; (void)n_in; (void)out_size;
  const float* X      = (const float*)d_in[0];
  const float* bbrel  = (const float*)d_in[1];
  const float* bbf    = (const float*)d_in[2];
  const int* batch    = (const int*)d_in[3];
  const int* xmask    = (const int*)d_in[4];
  const int* nmask    = (const int*)d_in[5];
  const float* w1     = (const float*)d_in[6];
  const float* b1     = (const float*)d_in[7];
  const float* w2     = (const float*)d_in[8];
  const float* b2     = (const float*)d_in[9];
  const float* wv     = (const float*)d_in[10];
  const float* bv     = (const float*)d_in[11];
  const float* wo     = (const float*)d_in[12];
  const float* bo     = (const float*)d_in[13];
  const float* wg     = (const float*)d_in[14];
  const float* bg     = (const float*)d_in[15];
  const float* wf     = (const float*)d_in[16];
  const float* bfb    = (const float*)d_in[17];
  const float* w_xca  = (const float*)d_in[18];
  const float* w_gate = (const float*)d_in[20];
  const float* b_gate = (const float*)d_in[21];
  const float* w_bb   = (const float*)d_in[22];

  if (ws_size < 18939904) return;
  char* ws = (char*)d_ws;
  uint32_t* bmp   = (uint32_t*)(ws + 0);          //  16KB
  int*      srcl  = (int*)(ws + 16384);           // 960KB
  float*    logit = (float*)(ws + 999424);        // 7.5MB
  float*    V     = (float*)(ws + 8863744);       // 9.0MB
  float*    Pn    = (float*)(ws + 8863744);       // 512KB (overlaps V; dead before vmat)
  float*    Pd    = (float*)(ws + 9388032);       // 512KB (overlaps V)
  float4*   Xw    = (float4*)(ws + 9912320);      //  64KB (overlaps V)
  float*    out   = (float*)d_out;

  prep_kernel<<<NN / 256, 256, 0, stream>>>(X, batch, xmask, Xw, bmp);
  nodeproj_kernel<<<NN / 8, 256, 0, stream>>>(bbf, nmask, w1, b1, Pn, Pd);
  select_kernel<<<NN, 256, 0, stream>>>(Xw, bmp, srcl);
  edge_kernel<<<NE / 8, 256, 0, stream>>>(srcl, Xw, Pn, Pd, w1, w2, b2, logit);
  vmat_kernel<<<(NN * LT) / 4, 256, 0, stream>>>(bbf, bbrel, nmask, wv, bv, V);
  node_kernel<<<NN, 64, 0, stream>>>(srcl, logit, V, wo, bo, wg, bg, wf, bfb,
                                     w_xca, w_gate, b_gate, w_bb, X, bbrel, nmask, out);
}

// Round 7
// 271.839 us; speedup vs baseline: 1.8525x; 1.0205x over previous
//
#include <hip/hip_runtime.h>
#include <hip/hip_bf16.h>
#include <stdint.h>

#define NN 4096
#define CS 2048           // chain size (NN / CHAINS)
#define KNN 20
#define LRK 40
#define EPN 60
#define NE (NN*EPN)
#define SPHC 35
#define BBCC 32
#define NHEAD 8
#define HVD 64
#define HCD 32
#define LT 9
#define MAXC 384

#define INVAL_D2 0xFFFFFFFEu
#define CONSUMED 0xFFFFFFFFu

__device__ __forceinline__ float fast_exp(float x) {   // e^x via v_exp_f32
  return __builtin_amdgcn_exp2f(x * 1.4426950408889634f);
}
__device__ __forceinline__ float fast_cos(float a) {   // cos(a), a in radians
  float rev = a * 0.15915494309189535f;
  rev = rev - __builtin_rintf(rev);                    // [-0.5, 0.5] revolutions
  return __builtin_amdgcn_cosf(rev);                   // v_cos: D = cos(2*pi*S)
}
__device__ __forceinline__ float fast_sin(float a) {
  float rev = a * 0.15915494309189535f;
  rev = rev - __builtin_rintf(rev);
  return __builtin_amdgcn_sinf(rev);
}

// ---- threefry2x32(key=[0,1]) -> -log(u) for jax uniform draw at (i,j) ----
__device__ __forceinline__ float neglogu_f(int i, int j) {
  uint32_t c = ((uint32_t)(i & 2047) << 12) | (uint32_t)j;
  const uint32_t ks0 = 0u, ks1 = 1u, ks2 = 0x1BD11BDBu;
  uint32_t x0 = c + ks0;
  uint32_t x1 = (c + 0x800000u) + ks1;
#define TF_R(r) { x0 += x1; x1 = (x1 << (r)) | (x1 >> (32 - (r))); x1 ^= x0; }
  TF_R(13) TF_R(15) TF_R(26) TF_R(6)   x0 += ks1; x1 += ks2 + 1u;
  TF_R(17) TF_R(29) TF_R(16) TF_R(24)  x0 += ks2; x1 += ks0 + 2u;
  TF_R(13) TF_R(15) TF_R(26) TF_R(6)   x0 += ks0; x1 += ks1 + 3u;
  TF_R(17) TF_R(29) TF_R(16) TF_R(24)  x0 += ks1; x1 += ks2 + 4u;
  TF_R(13) TF_R(15) TF_R(26) TF_R(6)   x0 += ks2; x1 += ks0 + 5u;
#undef TF_R
  uint32_t b = (i >= 2048) ? x1 : x0;
  float u = __uint_as_float((b >> 9) | 0x3F800000u) - 1.0f;
  u = u + 1.17549435e-38f;
  return -logf(u);
}

// ---- P0: Xw=(x,y,z,|x|^2), batch/mask word ----
__global__ void prep_kernel(const float* __restrict__ X,
                            const int* __restrict__ batch,
                            const int* __restrict__ xmask,
                            float4* __restrict__ Xw, uint32_t* __restrict__ bm) {
#pragma clang fp contract(off)
  int n = blockIdx.x * blockDim.x + threadIdx.x;
  if (n >= NN) return;
  float x = X[n*3+0], y = X[n*3+1], z = X[n*3+2];
  float x2 = (x*x + y*y) + z*z;
  Xw[n] = make_float4(x, y, z, x2);
  bm[n] = ((uint32_t)batch[n] << 1) | (xmask[n] ? 1u : 0u);
}

// ---- P1: per-node projections Pn = inv@W1[0:35], Pd = inv@W1[35:70] + b1 ----
__global__ __launch_bounds__(256) void nodeproj_kernel(const float* __restrict__ bbf,
                                                       const int* __restrict__ nmask,
                                                       const float* __restrict__ w1,
                                                       const float* __restrict__ b1,
                                                       float* __restrict__ Pn,
                                                       float* __restrict__ Pd) {
  int tid = threadIdx.x;
  int t = tid & 31;
  int n = blockIdx.x * 8 + (tid >> 5);
  float bv_ = bbf[(size_t)n * (LT*BBCC) + t];
  float an = 0.f, ad = b1[t];
  #pragma unroll 8
  for (int c = 0; c < BBCC; c++) {
    float bc = __shfl(bv_, (tid & 32) + c, 64);
    an = fmaf(bc, w1[c * HCD + t], an);
    ad = fmaf(bc, w1[(SPHC + c) * HCD + t], ad);
  }
  float nm = nmask[n] ? 1.f : 0.f;
  an = fmaf(nm, w1[34 * HCD + t], an);
  ad = fmaf(nm, w1[69 * HCD + t], ad);
  Pn[n * HCD + t] = an;
  Pd[n * HCD + t] = ad;
}

// ---- 2-level (11-bit bucket) exact k-th-smallest select + compaction ----
__device__ __forceinline__ void sel2l(uint32_t* val, uint32_t* hist2,
                                      uint32_t* candk, uint32_t* candp,
                                      uint32_t* sh, int* sel,
                                      int k, int base, int cb, int tid) {
  {
    uint4* h4 = (uint4*)hist2;
    uint4 z; z.x = 0; z.y = 0; z.z = 0; z.w = 0;
    h4[tid] = z; h4[tid + 256] = z;
  }
  if (tid == 0) { sh[2] = 0; sh[3] = 0; }
  __syncthreads();
  #pragma unroll
  for (int q = 0; q < 8; q++) {
    uint32_t key = val[tid + (q << 8)];
    atomicAdd(&hist2[key >> 21], 1u);
  }
  __syncthreads();
  uint32_t h[8], s = 0;
  #pragma unroll
  for (int q = 0; q < 8; q++) { h[q] = hist2[tid*8 + q]; s += h[q]; }
  uint32_t cum = s;
  #pragma unroll
  for (int off = 1; off < 64; off <<= 1) {
    uint32_t o = __shfl_up(cum, off, 64);
    if ((tid & 63) >= off) cum += o;
  }
  if ((tid & 63) == 63) sh[8 + (tid >> 6)] = cum;
  __syncthreads();
  uint32_t woff = 0;
  for (int w = 0; w < (tid >> 6); w++) woff += sh[8 + w];
  uint32_t cumAll = cum + woff;
  uint32_t cumBefore = cumAll - s;
  uint32_t rk = (uint32_t)k;
  if (rk > cumBefore && rk <= cumAll) {
    uint32_t rloc = rk - cumBefore, lp = 0;
    bool done = false;
    #pragma unroll
    for (int q = 0; q < 8; q++) {
      lp += h[q];
      if (!done && rloc <= lp) { sh[0] = (uint32_t)(tid*8 + q); sh[1] = rloc - (lp - h[q]); done = true; }
    }
  }
  __syncthreads();
  const uint32_t B = sh[0], r = sh[1];
  #pragma unroll
  for (int q = 0; q < 8; q++) {
    int pos = tid + (q << 8);
    uint32_t key = val[pos];
    if ((key >> 21) == B) {
      uint32_t idx = atomicAdd(&sh[2], 1u);
      if (idx < MAXC) { candk[idx] = key; candp[idx] = (uint32_t)pos; }
    }
  }
  __syncthreads();
  int m = (int)sh[2]; if (m > MAXC) m = MAXC;
  if (tid < 64) {
    for (int ci = tid; ci < m; ci += 64) {
      unsigned long long k64 = ((unsigned long long)candk[ci] << 32) | candp[ci];
      uint32_t rank = 0;
      for (int j = 0; j < m; j++) {
        unsigned long long o = ((unsigned long long)candk[j] << 32) | candp[j];
        rank += (o < k64) ? 1u : 0u;
      }
      if (rank == r - 1) { sh[0] = candk[ci]; sh[1] = candp[ci]; }
    }
  }
  __syncthreads();
  const uint32_t vstar = sh[0], istar = sh[1];
  #pragma unroll
  for (int q = 0; q < 8; q++) {
    int pos = tid + (q << 8);
    uint32_t key = val[pos];
    if (key < vstar || (key == vstar && (uint32_t)pos <= istar)) {
      uint32_t slot = atomicAdd(&sh[3], 1u);
      sel[base + (int)slot] = cb + pos;
    }
  }
  __syncthreads();
}

// ---- K1: per-row knn20 + gumbel-lr40 via chain-restricted 2-level select ----
__global__ __launch_bounds__(256) void select_kernel(const float4* __restrict__ Xw,
                                                     const uint32_t* __restrict__ bm,
                                                     int* __restrict__ srcO) {
#pragma clang fp contract(off)
  __shared__ uint32_t val[CS];
  __shared__ uint32_t hist2[2048];
  __shared__ uint32_t candk[MAXC];
  __shared__ uint32_t candp[MAXC];
  __shared__ uint32_t sh[12];
  __shared__ int sel[EPN];
  const int i = blockIdx.x, tid = threadIdx.x;
  const uint32_t bmi = bm[i];

  if (bmi & 1u) {
    if (tid < KNN) srcO[(size_t)i * EPN + tid] = tid;
    else if (tid < EPN) srcO[(size_t)i * EPN + tid] = tid - KNN;
    return;
  }
  const int cb = (int)(bmi >> 1) * CS;
  const float4 xi = Xw[i];

  #pragma unroll
  for (int q = 0; q < 8; q++) {
    int pos = tid + (q << 8);
    int j = cb + pos;
    float4 xj = Xw[j];
    uint32_t bmj = bm[j];
    bool inval = ((bmj & 1u) != 0u) || (j == i);
    float dot = xi.x*xj.x + xi.y*xj.y + xi.z*xj.z;
    float d2r = (xi.w + xj.w) - 2.0f*dot;
    float d2 = d2r > 0.0f ? d2r : 0.0f;
    val[pos] = inval ? INVAL_D2 : __float_as_uint(d2);
  }
  __syncthreads();

  sel2l(val, hist2, candk, candp, sh, sel, KNN, 0, cb, tid);

  if (tid < KNN) val[sel[tid] - cb] = CONSUMED;
  __syncthreads();

  // descending score == ascending w = (d2+1e-6)^1.5 * (-log u)   [w > 0]
  #pragma unroll
  for (int q = 0; q < 8; q++) {
    int pos = tid + (q << 8);
    uint32_t v = val[pos];
    uint32_t skey;
    if (v >= INVAL_D2) skey = CONSUMED;
    else {
      float d2p = __uint_as_float(v) + 1e-6f;
      float w = d2p * sqrtf(d2p) * neglogu_f(i, cb + pos);
      skey = __float_as_uint(w);
    }
    val[pos] = skey;
  }
  __syncthreads();

  sel2l(val, hist2, candk, candp, sh, sel, LRK, KNN, cb, tid);

  if (tid < EPN) srcO[(size_t)i * EPN + tid] = sel[tid];
}

// ---- K2: V[n,l,:] = so3_linear(node, wv, bv) ----
__global__ __launch_bounds__(256) void vmat_kernel(const float* __restrict__ bbf,
                                                   const float* __restrict__ bbrel,
                                                   const int* __restrict__ nmask,
                                                   const float* __restrict__ wv,
                                                   const float* __restrict__ bv,
                                                   float* __restrict__ V) {
  int row = blockIdx.x * 4 + (threadIdx.x >> 6);
  int d = threadIdx.x & 63;
  if (row >= NN * LT) return;
  int n = row / LT, l = row % LT;
  int li = (l == 0) ? 0 : (l < 4 ? 1 : 2);
  const float* w = wv + (size_t)li * SPHC * HVD;
  float acc = (l == 0) ? bv[d] : 0.f;
  const float* nb = bbf + (size_t)(n*LT + l) * BBCC;
  for (int c = 0; c < BBCC; c++) acc = fmaf(nb[c], w[c*HVD + d], acc);
  if (l >= 1 && l < 4) {
    for (int b = 0; b < 3; b++)
      acc = fmaf(bbrel[(size_t)(n*3 + b)*3 + (l-1)], w[(32+b)*HVD + d], acc);
  }
  if (l == 0) acc = fmaf(nmask[n] ? 1.f : 0.f, w[34*HVD + d], acc);
  V[(size_t)row * HVD + d] = acc;
}

// ---- K3: edge MLP -> logits; fast transcendentals (v_exp/v_sin/v_cos) ----
__global__ __launch_bounds__(256) void edge_kernel(const int* __restrict__ src,
                                                   const float4* __restrict__ Xw,
                                                   const float* __restrict__ Pn,
                                                   const float* __restrict__ Pd,
                                                   const float* __restrict__ w1,
                                                   const float* __restrict__ w2,
                                                   const float* __restrict__ b2,
                                                   float* __restrict__ logitO) {
  // freq table: exp(arange(0,16,2) * (-ln(10000)/16)) == 10^(-k/2)
  const float FR[8] = {1.0f, 0.31622776601683794f, 0.1f, 0.031622776601683794f,
                       0.01f, 0.0031622776601683794f, 0.001f, 0.00031622776601683794f};
  __shared__ float w1cf[BBCC][HCD];
  __shared__ float w2f[HCD][NHEAD];
  __shared__ float b2f[NHEAD];
  __shared__ float ef[8][BBCC];
  __shared__ float hbuf[8][HCD];
  int tid = threadIdx.x;
  for (int q = tid; q < BBCC*HCD; q += 256) w1cf[q >> 5][q & 31] = w1[70*HCD + q];
  if (tid < HCD*NHEAD) w2f[tid >> 3][tid & 7] = w2[tid];
  if (tid < NHEAD) b2f[tid] = b2[tid];
  int sub = tid >> 5, t = tid & 31;
  int e = blockIdx.x * 8 + sub;
  int d = e / EPN;
  int s = src[e];
  float4 xs = Xw[s], xd = Xw[d];
  float dx = xs.x - xd.x, dy = xs.y - xd.y, dz = xs.z - xd.z;
  float dist = sqrtf(dx*dx + dy*dy + dz*dz);
  if (t < 16) {
    float mu = (20.0f / 15.0f) * (float)t;
    float zz = (dist - mu) / 1.25f;
    ef[sub][t] = fast_exp(-zz * zz);
  } else {
    int k = t - 16;
    float del = (float)(s - d);
    float a = del * FR[k & 7];
    ef[sub][t] = (k < 8) ? fast_cos(a) : fast_sin(a);
  }
  __syncthreads();
  float a = Pn[s * HCD + t] + Pd[d * HCD + t];
  #pragma unroll
  for (int k = 0; k < BBCC; k++) a = fmaf(ef[sub][k], w1cf[k][t], a);
  hbuf[sub][t] = a / (1.f + fast_exp(-a));  // silu
  __syncthreads();
  if (tid < 64) {
    int e2 = tid >> 3, hh = tid & 7;
    float lg = b2f[hh];
    #pragma unroll
    for (int c = 0; c < HCD; c++) lg = fmaf(hbuf[e2][c], w2f[c][hh], lg);
    logitO[(size_t)(blockIdx.x * 8 + e2) * NHEAD + hh] = lg;
  }
}

// ---- K4: per-node softmax, aggregate, SO3 output chain ----
__global__ __launch_bounds__(64) void node_kernel(const int* __restrict__ src,
                                                  const float* __restrict__ logit,
                                                  const float* __restrict__ V,
                                                  const float* __restrict__ wo,
                                                  const float* __restrict__ bo,
                                                  const float* __restrict__ wg,
                                                  const float* __restrict__ bg,
                                                  const float* __restrict__ wf,
                                                  const float* __restrict__ bfb,
                                                  const float* __restrict__ w_xca,
                                                  const float* __restrict__ w_gate,
                                                  const float* __restrict__ b_gate,
                                                  const float* __restrict__ w_bb,
                                                  const float* __restrict__ X,
                                                  const float* __restrict__ bbrel,
                                                  const int* __restrict__ nmask,
                                                  float* __restrict__ out) {
  const int n = blockIdx.x, t = threadIdx.x;
  __shared__ float alpha[EPN][NHEAD];
  __shared__ int slist[EPN];
  __shared__ float agg[LT][HVD];
  __shared__ float o0[LT][BBCC];
  __shared__ float ofin[LT][BBCC];
  __shared__ float gate[BBCC];
  if (t < EPN) slist[t] = src[(size_t)n * EPN + t];
  for (int q = t; q < EPN * NHEAD; q += 64) alpha[q / NHEAD][q % NHEAD] = logit[(size_t)n * 480 + q];
  __syncthreads();
  if (t < NHEAD) {
    float m = -1e30f;
    for (int e = 0; e < EPN; e++) m = fmaxf(m, alpha[e][t]);
    float Z = 0.f;
    for (int e = 0; e < EPN; e++) { float p = expf(alpha[e][t] - m); alpha[e][t] = p; Z += p; }
    float iz = 1.f / (Z + 1e-9f);
    for (int e = 0; e < EPN; e++) alpha[e][t] *= iz;
  }
  __syncthreads();
  {
    const int h = t >> 3;
    float acc[LT];
    #pragma unroll
    for (int l = 0; l < LT; l++) acc[l] = 0.f;
    for (int e = 0; e < EPN; e++) {
      const float* Vp = V + (size_t)slist[e] * (LT * HVD) + t;
      float a = alpha[e][h];
      #pragma unroll
      for (int l = 0; l < LT; l++) acc[l] = fmaf(a, Vp[l * HVD], acc[l]);
    }
    #pragma unroll
    for (int l = 0; l < LT; l++) agg[l][t] = acc[l];
  }
  __syncthreads();
  for (int idx = t; idx < LT * BBCC; idx += 64) {
    int l = idx >> 5, d = idx & 31;
    int li = (l == 0) ? 0 : (l < 4 ? 1 : 2);
    float a = (l == 0) ? bo[d] : 0.f;
    const float* w = wo + (size_t)li * HVD * BBCC;
    for (int c = 0; c < HVD; c++) a = fmaf(agg[l][c], w[c * BBCC + d], a);
    o0[l][d] = a;
  }
  __syncthreads();
  if (t < BBCC) {
    float a = bg[t];
    for (int c = 0; c < BBCC; c++) a = fmaf(o0[0][c], wg[c * BBCC + t], a);
    gate[t] = a / (1.f + expf(-a));
  }
  __syncthreads();
  for (int idx = t; idx < LT * BBCC; idx += 64) {
    int l = idx >> 5, d = idx & 31;
    int li = (l == 0) ? 0 : (l < 4 ? 1 : 2);
    float a = (l == 0) ? bfb[d] : 0.f;
    const float* w = wf + (size_t)li * BBCC * BBCC;
    for (int c = 0; c < BBCC; c++) a = fmaf(o0[l][c], w[c * BBCC + d], a);
    float r = o0[l][d] + a * gate[d];
    ofin[l][d] = r;
    out[49152 + (size_t)n * 288 + idx] = r;
  }
  __syncthreads();
  float a2 = b_gate[0];
  for (int c = 0; c < BBCC; c++) a2 = fmaf(ofin[0][c], w_gate[c], a2);
  float g2 = fmaxf(a2, 0.f) + log1pf(expf(-fabsf(a2)));
  bool noise = nmask[n] != 0;
  if (t < 3) {
    float a = 0.f;
    for (int d2 = 0; d2 < BBCC; d2++) a = fmaf(ofin[1 + t][d2], w_xca[32 + d2], a);
    float nx = X[n * 3 + t] + (noise ? a * g2 : 0.f);
    out[(size_t)n * 3 + t] = nx;
  }
  if (t < 9) {
    int b = t / 3, c = t % 3;
    float a = 0.f;
    for (int d2 = 0; d2 < BBCC; d2++) a = fmaf(ofin[1 + c][d2], w_bb[(32 + d2) * 3 + b], a);
    float nb = bbrel[(size_t)(n * 3 + b) * 3 + c] + (noise ? a : 0.f);
    out[12288 + (size_t)n * 9 + b * 3 + c] = nb;
  }
}

extern "C" void kernel_launch(void* const* d_in, const int* in_sizes, int n_in,
                              void* d_out, int out_size, void* d_ws, size_t ws_size,
                              hipStream_t stream) {
  (void)in_sizes; (void)n_in; (void)out_size;
  const float* X      = (const float*)d_in[0];
  const float* bbrel  = (const float*)d_in[1];
  const float* bbf    = (const float*)d_in[2];
  const int* batch    = (const int*)d_in[3];
  const int* xmask    = (const int*)d_in[4];
  const int* nmask    = (const int*)d_in[5];
  const float* w1     = (const float*)d_in[6];
  const float* b1     = (const float*)d_in[7];
  const float* w2     = (const float*)d_in[8];
  const float* b2     = (const float*)d_in[9];
  const float* wv     = (const float*)d_in[10];
  const float* bv     = (const float*)d_in[11];
  const float* wo     = (const float*)d_in[12];
  const float* bo     = (const float*)d_in[13];
  const float* wg     = (const float*)d_in[14];
  const float* bg     = (const float*)d_in[15];
  const float* wf     = (const float*)d_in[16];
  const float* bfb    = (const float*)d_in[17];
  const float* w_xca  = (const float*)d_in[18];
  const float* w_gate = (const float*)d_in[20];
  const float* b_gate = (const float*)d_in[21];
  const float* w_bb   = (const float*)d_in[22];

  if (ws_size < 18939904) return;
  char* ws = (char*)d_ws;
  uint32_t* bmp   = (uint32_t*)(ws + 0);          //  16KB
  int*      srcl  = (int*)(ws + 16384);           // 960KB
  float*    logit = (float*)(ws + 999424);        // 7.5MB
  float*    V     = (float*)(ws + 8863744);       // 9.0MB
  float*    Pn    = (float*)(ws + 8863744);       // 512KB (overlaps V; dead before vmat)
  float*    Pd    = (float*)(ws + 9388032);       // 512KB (overlaps V)
  float4*   Xw    = (float4*)(ws + 9912320);      //  64KB (overlaps V)
  float*    out   = (float*)d_out;

  prep_kernel<<<NN / 256, 256, 0, stream>>>(X, batch, xmask, Xw, bmp);
  nodeproj_kernel<<<NN / 8, 256, 0, stream>>>(bbf, nmask, w1, b1, Pn, Pd);
  select_kernel<<<NN, 256, 0, stream>>>(Xw, bmp, srcl);
  edge_kernel<<<NE / 8, 256, 0, stream>>>(srcl, Xw, Pn, Pd, w1, w2, b2, logit);
  vmat_kernel<<<(NN * LT) / 4, 256, 0, stream>>>(bbf, bbrel, nmask, wv, bv, V);
  node_kernel<<<NN, 64, 0, stream>>>(srcl, logit, V, wo, bo, wg, bg, wf, bfb,
                                     w_xca, w_gate, b_gate, w_bb, X, bbrel, nmask, out);
}